// Round 11
// baseline (349.816 us; speedup 1.0000x reference)
//
#include <hip/hip_runtime.h>
#include <math.h>

#define DIMX 50
#define KK   51
#define NE   6
#define NB   8
#define NVOX ((size_t)NB * NE * DIMX * DIMX * DIMX)  // 6,000,000
#define MP   52                                      // padded M stride

typedef short bf16x8 __attribute__((ext_vector_type(8)));
typedef float f32x4  __attribute__((ext_vector_type(4)));

__device__ __forceinline__ unsigned short f2bf(float f) {
    unsigned u = __float_as_uint(f);
    u += 0x7fffu + ((u >> 16) & 1u);      // RNE; inputs finite
    return (unsigned short)(u >> 16);
}

// -------- taps + TRANSPOSED blur matrices: MT[m][e][c][o] = tap_m,e[c-o+25] --------
__global__ void taps_kernel(const float* __restrict__ sigma,
                            float* __restrict__ MT0, float* __restrict__ MT1,
                            float* __restrict__ maxval) {
    __shared__ float sg[NE * KK];
    __shared__ float sgs[NE * KK];
    __shared__ float ssum[NE];
    int t = threadIdx.x;
    if (t == 0) *maxval = 0.f;
    if (t < NE * KK) {
        int e = t / KK, i = t % KK;
        float d = (float)i - 25.0f;
        float var = sigma[e] * sigma[e];
        sg[t] = expf(-d * d / (2.f * var));
    }
    __syncthreads();
    if (t < NE) {
        float s = 0.f;
        for (int i = 0; i < KK; ++i) s += sg[t * KK + i];
        ssum[t] = s;
    }
    __syncthreads();
    if (t < NE * KK) {
        int e = t / KK;
        float S = 0.f;
        for (int e2 = 0; e2 < NE; ++e2) {
            float var2 = sigma[e2] * sigma[e2];
            float a2 = 1.f / (2.f * (float)M_PI * var2);
            float se = ssum[e2];
            S += a2 * se * se * se;
        }
        float var = sigma[e] * sigma[e];
        float a = 1.f / (2.f * (float)M_PI * var);
        sgs[t] = sg[t] * (a / S);
    }
    __syncthreads();
    // MT[m][e][c][o]: c in [0,50), o in [0,52) padded
    for (int i = t; i < 2 * NE * 50 * MP; i += 512) {
        int o = i % MP, c = (i / MP) % 50, e = (i / (MP * 50)) % NE, m = i / (MP * 50 * NE);
        int j = c - o + 25;
        float v = 0.f;
        if (o < 50 && j >= 0 && j < KK) v = (m == 0 ? sg : sgs)[e * KK + j];
        (m == 0 ? MT0 : MT1)[((e * 50) + c) * MP + o] = v;
    }
}

// ---------------- blur pass: per-plane 50x50 matmul, M^T staged in LDS ----------------
// AXIS = contracted axis (2=d, 1=h, 0=w). Block = one (be, f) plane.
// out[o][r] = sum_c M[o][c] * in[c][r];  lane = r; o-groups of 4 per wave.
// Inner loop: broadcast float4 of MT[c][o0..o0+3] + per-lane sp[c][r] + 4 FMA. No global.
template <int AXIS, bool DOMAX>
__global__ __launch_bounds__(256, 8)
void blur_mm(const float* __restrict__ in, float* __restrict__ out,
             const float* __restrict__ MT, float* __restrict__ maxval) {
    __shared__ float sp[50][MP];
    __shared__ float smt[50][MP];
    const int t  = threadIdx.x;
    const int f  = blockIdx.x % 50;
    const int be = blockIdx.x / 50;
    const int e  = be % NE;
    const float* base = in + (size_t)be * 125000;
    for (int i = t; i < 2500; i += 256) {
        int hi = i / 50, lo = i % 50;
        if (AXIS == 2)      sp[hi][lo] = base[hi * 2500 + f * 50 + lo];
        else if (AXIS == 1) sp[hi][lo] = base[f * 2500 + hi * 50 + lo];
        else                sp[lo][hi] = base[f * 2500 + hi * 50 + lo];
    }
    const float* mte = MT + (size_t)e * 50 * MP;
    for (int i = t; i < 50 * MP; i += 256) smt[i / MP][i % MP] = mte[i];
    __syncthreads();
    const int lane = t & 63;
    const int lr   = lane < 50 ? lane : 49;
    const int wv   = __builtin_amdgcn_readfirstlane(t >> 6);
    float* ob = out + (size_t)be * 125000;
    float m = 0.f;
    for (int g = wv; g < 13; g += 4) {
        const int o0 = g * 4;
        float a0 = 0.f, a1 = 0.f, a2 = 0.f, a3 = 0.f;
#pragma unroll 10
        for (int c = 0; c < 50; ++c) {
            float4 mv = *(const float4*)&smt[c][o0];   // broadcast (uniform addr)
            float v = sp[c][lr];
            a0 = fmaf(mv.x, v, a0);
            a1 = fmaf(mv.y, v, a1);
            a2 = fmaf(mv.z, v, a2);
            a3 = fmaf(mv.w, v, a3);
        }
        if (lane < 50) {
            float accs[4] = {a0, a1, a2, a3};
#pragma unroll
            for (int k = 0; k < 4; ++k) {
                int o = o0 + k;
                if (o < 50) {
                    size_t addr;
                    if (AXIS == 2)      addr = (size_t)o * 2500 + f * 50 + lane;
                    else if (AXIS == 1) addr = (size_t)f * 2500 + o * 50 + lane;
                    else                addr = (size_t)f * 2500 + lane * 50 + o;
                    ob[addr] = accs[k];
                    if (DOMAX) m = fmaxf(m, accs[k]);
                }
            }
        }
    }
    if (DOMAX) {
        for (int o = 32; o; o >>= 1) m = fmaxf(m, __shfl_xor(m, o));
        if ((t & 63) == 0) atomicMax((int*)maxval, __float_as_int(m));
    }
}

// ---------------- T1: blur-out fp32 [b*6+e][z][y][x] -> X1 bf16 channels-last [b][z][y][x][16] ----------------
__global__ __launch_bounds__(256)
void t1_kernel(const float* __restrict__ A, unsigned short* __restrict__ X1) {
    const int z = blockIdx.x % 50, b = blockIdx.x / 50;
    const float* ab = A + (size_t)b * 6 * 125000 + z * 2500;
    unsigned short* xb = X1 + ((size_t)b * 125000 + (size_t)z * 2500) * 16;
    for (int i = threadIdx.x; i < 2500; i += 256) {
        unsigned short v[6];
#pragma unroll
        for (int e = 0; e < 6; ++e) v[e] = f2bf(ab[(size_t)e * 125000 + i]);
        uint4 q0, q1;
        q0.x = v[0] | ((unsigned)v[1] << 16);
        q0.y = v[2] | ((unsigned)v[3] << 16);
        q0.z = v[4] | ((unsigned)v[5] << 16);
        q0.w = 0u;
        q1.x = 0u; q1.y = 0u; q1.z = 0u; q1.w = 0u;
        *(uint4*)(xb + (size_t)i * 16)     = q0;
        *(uint4*)(xb + (size_t)i * 16 + 8) = q1;
    }
}

// ---------------- weight prep: generic B-fragment pack [cog][tap][ch][lane][8] ----------------
__global__ void wprep_kernel(const float* __restrict__ W, unsigned short* __restrict__ out,
                             int CIN, int NCH, int NCOG) {
    int idx = blockIdx.x * 256 + threadIdx.x;
    int total = NCOG * 27 * NCH * 64;
    if (idx >= total) return;
    int l = idx & 63;
    int r = idx >> 6;
    int ch = r % NCH; r /= NCH;
    int tap = r % 27;
    int cog = r / 27;
    int co = cog * 16 + (l & 15);
    unsigned short v[8];
#pragma unroll
    for (int j = 0; j < 8; ++j) {
        int ci = ch * 32 + (l >> 4) * 8 + j;
        v[j] = (ci < CIN) ? f2bf(W[((size_t)co * CIN + ci) * 27 + tap]) : (unsigned short)0;
    }
    uint4 q;
    q.x = v[0] | ((unsigned)v[1] << 16);
    q.y = v[2] | ((unsigned)v[3] << 16);
    q.z = v[4] | ((unsigned)v[5] << 16);
    q.w = v[6] | ((unsigned)v[7] << 16);
    ((uint4*)out)[idx] = q;
}

// ---------------- conv1 weight prep: dual-x-tap packing [cog][18][lane][8] ----------------
__global__ void wprep1_kernel(const float* __restrict__ W, unsigned short* __restrict__ out) {
    int idx = blockIdx.x * 64 + threadIdx.x;
    if (idx >= 2 * 18 * 64) return;
    int l = idx & 63;
    int r = idx >> 6;
    int tg = r % 18;
    int cog = r / 18;
    int kzky = tg >> 1, kxg = tg & 1;
    int co = cog * 16 + (l & 15);
    unsigned short v[8];
#pragma unroll
    for (int j = 0; j < 8; ++j) {
        int k = (l >> 4) * 8 + j;
        int ci = k & 15, xsel = k >> 4;
        int kx = (kxg == 0) ? xsel : (xsel == 0 ? 2 : -1);
        float wv = 0.f;
        if (ci < 6 && kx >= 0) wv = W[((size_t)co * 6 + ci) * 27 + kzky * 3 + kx];
        v[j] = f2bf(wv);
    }
    uint4 q;
    q.x = v[0] | ((unsigned)v[1] << 16);
    q.y = v[2] | ((unsigned)v[3] << 16);
    q.z = v[4] | ((unsigned)v[5] << 16);
    q.w = v[6] | ((unsigned)v[7] << 16);
    ((uint4*)out)[idx] = q;
}

// ---------------- conv1 MFMA: X1[50^3][16] -> X2[24^3][32], /max + bias + pool + relu ----------------
__global__ __launch_bounds__(64, 3)
void conv1_mfma(const unsigned short* __restrict__ X1, const unsigned short* __restrict__ wp1,
                const float* __restrict__ bias, const float* __restrict__ maxval,
                unsigned short* __restrict__ X2) {
    const int l = threadIdx.x, lm = l & 15, lg = l >> 4;
    const int s0 = blockIdx.x * 8;
    const int r0 = s0 / 72;                 // uniform in block (8 | 72)
    const int cog = r0 % 2;
    const int pz  = (r0 / 2) % 24;
    const int b   = r0 / 48;
    uint4 B[18];
    const uint4* wpb = (const uint4*)wp1 + cog * 18 * 64;
#pragma unroll
    for (int t = 0; t < 18; ++t) B[t] = wpb[t * 64 + l];
    const float rmv = 1.0f / (*maxval);
    const float bia = bias[cog * 16 + lm];
    const unsigned short* Xb = X1 + (size_t)b * 125000 * 16;
    const f32x4 z4 = {0.f, 0.f, 0.f, 0.f};
#pragma unroll 1
    for (int si = 0; si < 8; ++si) {
        const int sid = s0 + si;
        const int xs = sid % 3;
        const int py = (sid / 3) % 24;
        const int x0 = xs * 16;
        f32x4 acc[2][2];
#pragma unroll
        for (int cz = 0; cz < 2; ++cz)
#pragma unroll
            for (int cy = 0; cy < 2; ++cy) acc[cz][cy] = z4;
#pragma unroll
        for (int zi = 0; zi < 4; ++zi) {
            const int zin = 2 * pz + zi;
#pragma unroll
            for (int yi = 0; yi < 4; ++yi) {
                const int yin = 2 * py + yi;
                const unsigned short* rowb = Xb + (size_t)(zin * 50 + yin) * 50 * 16;
#pragma unroll
                for (int xg = 0; xg < 2; ++xg) {
                    bf16x8 a = *(const bf16x8*)(rowb + (x0 + 2 * xg + lm) * 16 + lg * 8);
#pragma unroll
                    for (int cz = 0; cz < 2; ++cz) {
                        const int kz = zi - cz;
                        if (kz < 0 || kz > 2) continue;
#pragma unroll
                        for (int cy = 0; cy < 2; ++cy) {
                            const int ky = yi - cy;
                            if (ky < 0 || ky > 2) continue;
                            const int tg = (kz * 3 + ky) * 2 + xg;
                            acc[cz][cy] = __builtin_amdgcn_mfma_f32_16x16x32_bf16(
                                a, *(const bf16x8*)&B[tg], acc[cz][cy], 0, 0, 0);
                        }
                    }
                }
            }
        }
        const int co = cog * 16 + lm;
#pragma unroll
        for (int ip = 0; ip < 2; ++ip) {
            float m0 = fmaxf(fmaxf(acc[0][0][2 * ip], acc[0][1][2 * ip]),
                             fmaxf(acc[1][0][2 * ip], acc[1][1][2 * ip]));
            float m1 = fmaxf(fmaxf(acc[0][0][2 * ip + 1], acc[0][1][2 * ip + 1]),
                             fmaxf(acc[1][0][2 * ip + 1], acc[1][1][2 * ip + 1]));
            float o = fmaxf(fmaxf(m0, m1) * rmv + bia, 0.f);
            int px = x0 / 2 + lg * 2 + ip;
            X2[((((size_t)b * 24 + pz) * 24 + py) * 24 + px) * 32 + co] = f2bf(o);
        }
    }
}

// ---------------- generic MFMA conv (conv2/conv3): bias + pool + relu -> bf16 ch-last ----------------
template <int DIN, int DP, int CI, int NCH, int NCOG, int NPY, int NXS, int SPB, int NPZ>
__global__ __launch_bounds__(64, 3)
void convN_mfma(const unsigned short* __restrict__ X, const unsigned short* __restrict__ wp,
                const float* __restrict__ bias, unsigned short* __restrict__ Y, int COUT) {
    const int l = threadIdx.x, lm = l & 15, lg = l >> 4;
    const int s0 = blockIdx.x * SPB;
    const int r0 = s0 / (NPY * NXS);        // uniform in block (SPB | NPY*NXS)
    const int cog = r0 % NCOG;
    const int pz  = (r0 / NCOG) % NPZ;
    const int b   = r0 / (NCOG * NPZ);
    const float bia = bias[cog * 16 + lm];
    const unsigned short* Xb = X + (size_t)b * DIN * DIN * DIN * CI;
    const uint4* wp4 = (const uint4*)wp;
    const f32x4 z4 = {0.f, 0.f, 0.f, 0.f};
#pragma unroll 1
    for (int si = 0; si < SPB; ++si) {
        const int sid = s0 + si;
        const int xs = sid % NXS;
        const int py = (sid / NXS) % NPY;
        const int x0 = xs * 16;
        int xo[3];
#pragma unroll
        for (int kx = 0; kx < 3; ++kx) {
            int xin = x0 + kx + lm;
            if (xin > DIN - 1) xin = DIN - 1;     // garbage rows masked at store
            xo[kx] = xin * CI + lg * 8;
        }
        f32x4 acc[2][2];
#pragma unroll
        for (int cz = 0; cz < 2; ++cz)
#pragma unroll
            for (int cy = 0; cy < 2; ++cy) acc[cz][cy] = z4;
#pragma unroll 1
        for (int ch = 0; ch < NCH; ++ch) {
            uint4 B[27];
            const uint4* wpb = wp4 + ((size_t)cog * 27 * NCH + ch) * 64;
#pragma unroll
            for (int t = 0; t < 27; ++t) B[t] = wpb[(size_t)t * NCH * 64 + l];
            const unsigned short* Xc = Xb + ch * 32;
#pragma unroll
            for (int zi = 0; zi < 4; ++zi) {
                const int zin = 2 * pz + zi;
#pragma unroll
                for (int yi = 0; yi < 4; ++yi) {
                    const int yin = 2 * py + yi;
                    const unsigned short* rowb = Xc + (size_t)(zin * DIN + yin) * DIN * CI;
#pragma unroll
                    for (int kx = 0; kx < 3; ++kx) {
                        bf16x8 a = *(const bf16x8*)(rowb + xo[kx]);
#pragma unroll
                        for (int cz = 0; cz < 2; ++cz) {
                            const int kz = zi - cz;
                            if (kz < 0 || kz > 2) continue;
#pragma unroll
                            for (int cy = 0; cy < 2; ++cy) {
                                const int ky = yi - cy;
                                if (ky < 0 || ky > 2) continue;
                                const int tap = (kz * 3 + ky) * 3 + kx;
                                acc[cz][cy] = __builtin_amdgcn_mfma_f32_16x16x32_bf16(
                                    a, *(const bf16x8*)&B[tap], acc[cz][cy], 0, 0, 0);
                            }
                        }
                    }
                }
            }
        }
        const int co = cog * 16 + lm;
#pragma unroll
        for (int ip = 0; ip < 2; ++ip) {
            float m0 = fmaxf(fmaxf(acc[0][0][2 * ip], acc[0][1][2 * ip]),
                             fmaxf(acc[1][0][2 * ip], acc[1][1][2 * ip]));
            float m1 = fmaxf(fmaxf(acc[0][0][2 * ip + 1], acc[0][1][2 * ip + 1]),
                             fmaxf(acc[1][0][2 * ip + 1], acc[1][1][2 * ip + 1]));
            float o = fmaxf(fmaxf(m0, m1) + bia, 0.f);
            int px = x0 / 2 + lg * 2 + ip;
            if (px < DP)
                Y[((((size_t)b * DP + pz) * DP + py) * DP + px) * COUT + co] = f2bf(o);
        }
    }
}

// ---------------- conv4: channels-last bf16 in, fp32 weights; wave per (b,co) ----------------
__global__ void conv4_kernel(const unsigned short* __restrict__ X4, const float* __restrict__ w,
                             const float* __restrict__ bias, float* __restrict__ out) {
    int wid = (int)((blockIdx.x * blockDim.x + threadIdx.x) >> 6);
    int lane = threadIdx.x & 63;
    if (wid >= NB * 256) return;
    int b = wid >> 8, co = wid & 255;
    float acc[8];
#pragma unroll
    for (int i = 0; i < 8; ++i) acc[i] = 0.f;
    for (int half = 0; half < 2; ++half) {
        int ci = lane + half * 64;
        float win[64];
#pragma unroll
        for (int v = 0; v < 64; ++v)
            win[v] = __uint_as_float((unsigned)X4[((size_t)b * 64 + v) * 128 + ci] << 16);
        const float* wc = w + ((size_t)co * 128 + ci) * 27;
        float wr[27];
#pragma unroll
        for (int i = 0; i < 27; ++i) wr[i] = wc[i];
#pragma unroll
        for (int kz = 0; kz < 3; ++kz)
#pragma unroll
            for (int ky = 0; ky < 3; ++ky)
#pragma unroll
                for (int kx = 0; kx < 3; ++kx) {
                    float wv = wr[(kz * 3 + ky) * 3 + kx];
#pragma unroll
                    for (int oz = 0; oz < 2; ++oz)
#pragma unroll
                        for (int oy = 0; oy < 2; ++oy)
#pragma unroll
                            for (int ox = 0; ox < 2; ++ox)
                                acc[(oz * 2 + oy) * 2 + ox] =
                                    fmaf(wv, win[((oz + kz) * 4 + (oy + ky)) * 4 + ox + kx],
                                         acc[(oz * 2 + oy) * 2 + ox]);
                }
    }
#pragma unroll
    for (int o = 32; o; o >>= 1)
#pragma unroll
        for (int i = 0; i < 8; ++i) acc[i] += __shfl_xor(acc[i], o);
    if (lane == 0) {
        float m = acc[0];
#pragma unroll
        for (int i = 1; i < 8; ++i) m = fmaxf(m, acc[i]);
        out[(size_t)b * 256 + co] = fmaxf(m + bias[co], 0.f);
    }
}

// ---------------- FC head: (8,256) -> relu(128) -> 29 ----------------
__global__ void head_kernel(const float* __restrict__ v,
                            const float* __restrict__ fw1, const float* __restrict__ fb1,
                            const float* __restrict__ fw2, const float* __restrict__ fb2,
                            float* __restrict__ out) {
    int b = blockIdx.x, t = threadIdx.x;
    __shared__ float sv[256];
    __shared__ float s1[128];
    sv[t] = v[b * 256 + t];
    sv[t + 128] = v[b * 256 + t + 128];
    __syncthreads();
    float acc = fb1[t];
    const float* wr = fw1 + t * 256;
    for (int k = 0; k < 256; ++k) acc = fmaf(wr[k], sv[k], acc);
    s1[t] = fmaxf(acc, 0.f);
    __syncthreads();
    if (t < 29) {
        float a2 = fb2[t];
        const float* w2 = fw2 + t * 128;
        for (int k = 0; k < 128; ++k) a2 = fmaf(w2[k], s1[k], a2);
        out[b * 29 + t] = a2;
    }
}

extern "C" void kernel_launch(void* const* d_in, const int* in_sizes, int n_in,
                              void* d_out, int out_size, void* d_ws, size_t ws_size,
                              hipStream_t stream) {
    const float* x     = (const float*)d_in[0];
    const float* sigma = (const float*)d_in[1];
    const float* w1    = (const float*)d_in[2];
    const float* b1    = (const float*)d_in[3];
    const float* w2    = (const float*)d_in[4];
    const float* b2    = (const float*)d_in[5];
    const float* w3    = (const float*)d_in[6];
    const float* b3    = (const float*)d_in[7];
    const float* w4    = (const float*)d_in[8];
    const float* b4    = (const float*)d_in[9];
    const float* fw1   = (const float*)d_in[10];
    const float* fb1   = (const float*)d_in[11];
    const float* fw2   = (const float*)d_in[12];
    const float* fb2   = (const float*)d_in[13];
    float* out = (float*)d_out;

    // ---- workspace layout (~65.3 MB) ----
    float* A = (float*)d_ws;                                  // 6,000,000 f
    unsigned short* X1 = (unsigned short*)(A + NVOX);         // 16,000,064 ush (incl. pad)
    float* Bf = (float*)X1;                                   // blur tmp overlays X1 (dead before T1)
    unsigned short* X2  = X1 + 16000064;                      // 3,538,944
    unsigned short* X3  = X2 + 3538944;                       // 681,472
    unsigned short* X4  = X3 + 681472;                        // 65,536
    unsigned short* wp1 = X4 + 65536;                         // 18,432
    unsigned short* wp2 = wp1 + 18432;                        // 55,296
    unsigned short* wp3 = wp2 + 55296;                        // 221,184
    float* MT0 = (float*)(wp3 + 221184);                      // 6*50*52
    float* MT1 = MT0 + NE * 50 * MP;                          // 6*50*52
    float* mx  = MT1 + NE * 50 * MP;                          // 1
    float* v4  = mx + 1;                                      // 2048 f

    taps_kernel<<<1, 512, 0, stream>>>(sigma, MT0, MT1, mx);

    // separable blur: 3 per-plane 50x50 matmuls, M^T in LDS (scaled taps + max in last)
    blur_mm<2, false><<<NB * NE * 50, 256, 0, stream>>>(x,  A,  MT0, nullptr);
    blur_mm<1, false><<<NB * NE * 50, 256, 0, stream>>>(A,  Bf, MT0, nullptr);
    blur_mm<0, true> <<<NB * NE * 50, 256, 0, stream>>>(Bf, A,  MT1, mx);

    // channels-last bf16 conversion + weight fragment packing
    t1_kernel<<<400, 256, 0, stream>>>(A, X1);
    wprep1_kernel<<<36, 64, 0, stream>>>(w1, wp1);
    wprep_kernel<<<27, 256, 0, stream>>>(w2, wp2, 32, 1, 4);
    wprep_kernel<<<108, 256, 0, stream>>>(w3, wp3, 64, 2, 8);

    // conv1: MFMA shift-GEMM, dual-x-tap K packing
    conv1_mfma<<<3456, 64, 0, stream>>>(X1, wp1, b1, mx, X2);
    // conv2
    convN_mfma<24, 11, 32, 1, 4, 11, 2, 2, 11><<<3872, 64, 0, stream>>>(X2, wp2, b2, X3, 64);
    // conv3
    convN_mfma<11, 4, 64, 2, 8, 4, 1, 1, 4><<<1024, 64, 0, stream>>>(X3, wp3, b3, X4, 128);

    // conv4 (VALU, channels-last bf16 in) + head
    conv4_kernel<<<512, 256, 0, stream>>>(X4, w4, b4, v4);
    head_kernel<<<8, 128, 0, stream>>>(v4, fw1, fb1, fw2, fb2, out);
}

// Round 12
// 349.496 us; speedup vs baseline: 1.0009x; 1.0009x over previous
//
#include <hip/hip_runtime.h>
#include <math.h>

#define DIMX 50
#define KK   51
#define NE   6
#define NB   8
#define NVOX ((size_t)NB * NE * DIMX * DIMX * DIMX)  // 6,000,000
#define MP   52                                      // padded M stride

typedef short bf16x8 __attribute__((ext_vector_type(8)));
typedef float f32x4  __attribute__((ext_vector_type(4)));

__device__ __forceinline__ unsigned short f2bf(float f) {
    unsigned u = __float_as_uint(f);
    u += 0x7fffu + ((u >> 16) & 1u);      // RNE; inputs finite
    return (unsigned short)(u >> 16);
}

// -------- taps + TRANSPOSED blur matrices: MT[m][e][c][o] = tap_m,e[c-o+25] --------
__global__ void taps_kernel(const float* __restrict__ sigma,
                            float* __restrict__ MT0, float* __restrict__ MT1,
                            float* __restrict__ maxval) {
    __shared__ float sg[NE * KK];
    __shared__ float sgs[NE * KK];
    __shared__ float ssum[NE];
    int t = threadIdx.x;
    if (t == 0) *maxval = 0.f;
    if (t < NE * KK) {
        int e = t / KK, i = t % KK;
        float d = (float)i - 25.0f;
        float var = sigma[e] * sigma[e];
        sg[t] = expf(-d * d / (2.f * var));
    }
    __syncthreads();
    if (t < NE) {
        float s = 0.f;
        for (int i = 0; i < KK; ++i) s += sg[t * KK + i];
        ssum[t] = s;
    }
    __syncthreads();
    if (t < NE * KK) {
        int e = t / KK;
        float S = 0.f;
        for (int e2 = 0; e2 < NE; ++e2) {
            float var2 = sigma[e2] * sigma[e2];
            float a2 = 1.f / (2.f * (float)M_PI * var2);
            float se = ssum[e2];
            S += a2 * se * se * se;
        }
        float var = sigma[e] * sigma[e];
        float a = 1.f / (2.f * (float)M_PI * var);
        sgs[t] = sg[t] * (a / S);
    }
    __syncthreads();
    // MT[m][e][c][o]: c in [0,50), o in [0,52) padded
    for (int i = t; i < 2 * NE * 50 * MP; i += 512) {
        int o = i % MP, c = (i / MP) % 50, e = (i / (MP * 50)) % NE, m = i / (MP * 50 * NE);
        int j = c - o + 25;
        float v = 0.f;
        if (o < 50 && j >= 0 && j < KK) v = (m == 0 ? sg : sgs)[e * KK + j];
        (m == 0 ? MT0 : MT1)[((e * 50) + c) * MP + o] = v;
    }
}

// ---------------- blur pass: per-plane 50x50 matmul, M^T + plane in LDS ----------------
// AXIS = contracted axis (2=d, 1=h, 0=w). Block = one (be, f) plane.
// AXIS 2/1: lane = r (output row), 4-o groups, M broadcast.  Writes lane-contiguous.
// AXIS 0:   lane = o (flip), 4-r groups, plane broadcast, M per-lane. Writes lane-contiguous.
// Inner loop: 10-wide load batch (independent LDS reads) then 40 FMAs -> latency amortized.
template <int AXIS, bool DOMAX>
__global__ __launch_bounds__(256, 4)
void blur_mm(const float* __restrict__ in, float* __restrict__ out,
             const float* __restrict__ MT, float* __restrict__ maxval) {
    __shared__ float sp[50][MP];
    __shared__ float smt[50][MP];
    const int t  = threadIdx.x;
    const int f  = blockIdx.x % 50;
    const int be = blockIdx.x / 50;
    const int e  = be % NE;
    const float* base = in + (size_t)be * 125000;
    for (int i = t; i < 2500; i += 256) {
        int hi = i / 50, lo = i % 50;
        if (AXIS == 2)      sp[hi][lo] = base[hi * 2500 + f * 50 + lo];
        else if (AXIS == 1) sp[hi][lo] = base[f * 2500 + hi * 50 + lo];
        else                sp[lo][hi] = base[f * 2500 + hi * 50 + lo];  // sp[w][h]
    }
    const float* mte = MT + (size_t)e * 50 * MP;
    for (int i = t; i < 50 * MP; i += 256) (&smt[0][0])[i] = mte[i];
    __syncthreads();
    const int lane = t & 63;
    const int lr   = lane < 50 ? lane : 49;
    const int wv   = __builtin_amdgcn_readfirstlane(t >> 6);
    float* ob = out + (size_t)be * 125000;
    float m = 0.f;
    for (int g = wv; g < 13; g += 4) {
        const int q0 = g * 4;           // o0 (AXIS 2/1) or r0 (AXIS 0)
        float a0 = 0.f, a1 = 0.f, a2 = 0.f, a3 = 0.f;
#pragma unroll 1
        for (int c0 = 0; c0 < 50; c0 += 10) {
            float4 bv[10];
            float  pv[10];
#pragma unroll
            for (int j = 0; j < 10; ++j) {
                if (AXIS == 0) {
                    bv[j] = *(const float4*)&sp[c0 + j][q0];    // broadcast: in[c][r0..r0+3]
                    pv[j] = smt[c0 + j][lr];                    // per-lane: M[o=lane][c]
                } else {
                    bv[j] = *(const float4*)&smt[c0 + j][q0];   // broadcast: M^T[c][o0..o0+3]
                    pv[j] = sp[c0 + j][lr];                     // per-lane: in[c][r=lane]
                }
            }
#pragma unroll
            for (int j = 0; j < 10; ++j) {
                a0 = fmaf(bv[j].x, pv[j], a0);
                a1 = fmaf(bv[j].y, pv[j], a1);
                a2 = fmaf(bv[j].z, pv[j], a2);
                a3 = fmaf(bv[j].w, pv[j], a3);
            }
        }
        if (lane < 50) {
            float accs[4] = {a0, a1, a2, a3};
#pragma unroll
            for (int k = 0; k < 4; ++k) {
                int q = q0 + k;
                if (q < 50) {
                    size_t addr;
                    if (AXIS == 2)      addr = (size_t)q * 2500 + f * 50 + lane;   // [o][f][r]
                    else if (AXIS == 1) addr = (size_t)f * 2500 + q * 50 + lane;   // [f][o][r]
                    else                addr = (size_t)f * 2500 + q * 50 + lane;   // [f][r][o=lane]
                    ob[addr] = accs[k];
                    if (DOMAX) m = fmaxf(m, accs[k]);
                }
            }
        }
    }
    if (DOMAX) {
        for (int o = 32; o; o >>= 1) m = fmaxf(m, __shfl_xor(m, o));
        if ((t & 63) == 0) atomicMax((int*)maxval, __float_as_int(m));
    }
}

// ---------------- T1: blur-out fp32 [b*6+e][z][y][x] -> X1 bf16 channels-last [b][z][y][x][16] ----------------
__global__ __launch_bounds__(256)
void t1_kernel(const float* __restrict__ A, unsigned short* __restrict__ X1) {
    const int z = blockIdx.x % 50, b = blockIdx.x / 50;
    const float* ab = A + (size_t)b * 6 * 125000 + z * 2500;
    unsigned short* xb = X1 + ((size_t)b * 125000 + (size_t)z * 2500) * 16;
    for (int i = threadIdx.x; i < 2500; i += 256) {
        unsigned short v[6];
#pragma unroll
        for (int e = 0; e < 6; ++e) v[e] = f2bf(ab[(size_t)e * 125000 + i]);
        uint4 q0, q1;
        q0.x = v[0] | ((unsigned)v[1] << 16);
        q0.y = v[2] | ((unsigned)v[3] << 16);
        q0.z = v[4] | ((unsigned)v[5] << 16);
        q0.w = 0u;
        q1.x = 0u; q1.y = 0u; q1.z = 0u; q1.w = 0u;
        *(uint4*)(xb + (size_t)i * 16)     = q0;
        *(uint4*)(xb + (size_t)i * 16 + 8) = q1;
    }
}

// ---------------- weight prep: generic B-fragment pack [cog][tap][ch][lane][8] ----------------
__global__ void wprep_kernel(const float* __restrict__ W, unsigned short* __restrict__ out,
                             int CIN, int NCH, int NCOG) {
    int idx = blockIdx.x * 256 + threadIdx.x;
    int total = NCOG * 27 * NCH * 64;
    if (idx >= total) return;
    int l = idx & 63;
    int r = idx >> 6;
    int ch = r % NCH; r /= NCH;
    int tap = r % 27;
    int cog = r / 27;
    int co = cog * 16 + (l & 15);
    unsigned short v[8];
#pragma unroll
    for (int j = 0; j < 8; ++j) {
        int ci = ch * 32 + (l >> 4) * 8 + j;
        v[j] = (ci < CIN) ? f2bf(W[((size_t)co * CIN + ci) * 27 + tap]) : (unsigned short)0;
    }
    uint4 q;
    q.x = v[0] | ((unsigned)v[1] << 16);
    q.y = v[2] | ((unsigned)v[3] << 16);
    q.z = v[4] | ((unsigned)v[5] << 16);
    q.w = v[6] | ((unsigned)v[7] << 16);
    ((uint4*)out)[idx] = q;
}

// ---------------- conv1 weight prep: dual-x-tap packing [cog][18][lane][8] ----------------
__global__ void wprep1_kernel(const float* __restrict__ W, unsigned short* __restrict__ out) {
    int idx = blockIdx.x * 64 + threadIdx.x;
    if (idx >= 2 * 18 * 64) return;
    int l = idx & 63;
    int r = idx >> 6;
    int tg = r % 18;
    int cog = r / 18;
    int kzky = tg >> 1, kxg = tg & 1;
    int co = cog * 16 + (l & 15);
    unsigned short v[8];
#pragma unroll
    for (int j = 0; j < 8; ++j) {
        int k = (l >> 4) * 8 + j;
        int ci = k & 15, xsel = k >> 4;
        int kx = (kxg == 0) ? xsel : (xsel == 0 ? 2 : -1);
        float wv = 0.f;
        if (ci < 6 && kx >= 0) wv = W[((size_t)co * 6 + ci) * 27 + kzky * 3 + kx];
        v[j] = f2bf(wv);
    }
    uint4 q;
    q.x = v[0] | ((unsigned)v[1] << 16);
    q.y = v[2] | ((unsigned)v[3] << 16);
    q.z = v[4] | ((unsigned)v[5] << 16);
    q.w = v[6] | ((unsigned)v[7] << 16);
    ((uint4*)out)[idx] = q;
}

// ---------------- conv1 MFMA: X1[50^3][16] -> X2[24^3][32], /max + bias + pool + relu ----------------
__global__ __launch_bounds__(64, 3)
void conv1_mfma(const unsigned short* __restrict__ X1, const unsigned short* __restrict__ wp1,
                const float* __restrict__ bias, const float* __restrict__ maxval,
                unsigned short* __restrict__ X2) {
    const int l = threadIdx.x, lm = l & 15, lg = l >> 4;
    const int s0 = blockIdx.x * 8;
    const int r0 = s0 / 72;                 // uniform in block (8 | 72)
    const int cog = r0 % 2;
    const int pz  = (r0 / 2) % 24;
    const int b   = r0 / 48;
    uint4 B[18];
    const uint4* wpb = (const uint4*)wp1 + cog * 18 * 64;
#pragma unroll
    for (int t = 0; t < 18; ++t) B[t] = wpb[t * 64 + l];
    const float rmv = 1.0f / (*maxval);
    const float bia = bias[cog * 16 + lm];
    const unsigned short* Xb = X1 + (size_t)b * 125000 * 16;
    const f32x4 z4 = {0.f, 0.f, 0.f, 0.f};
#pragma unroll 1
    for (int si = 0; si < 8; ++si) {
        const int sid = s0 + si;
        const int xs = sid % 3;
        const int py = (sid / 3) % 24;
        const int x0 = xs * 16;
        f32x4 acc[2][2];
#pragma unroll
        for (int cz = 0; cz < 2; ++cz)
#pragma unroll
            for (int cy = 0; cy < 2; ++cy) acc[cz][cy] = z4;
#pragma unroll
        for (int zi = 0; zi < 4; ++zi) {
            const int zin = 2 * pz + zi;
#pragma unroll
            for (int yi = 0; yi < 4; ++yi) {
                const int yin = 2 * py + yi;
                const unsigned short* rowb = Xb + (size_t)(zin * 50 + yin) * 50 * 16;
#pragma unroll
                for (int xg = 0; xg < 2; ++xg) {
                    bf16x8 a = *(const bf16x8*)(rowb + (x0 + 2 * xg + lm) * 16 + lg * 8);
#pragma unroll
                    for (int cz = 0; cz < 2; ++cz) {
                        const int kz = zi - cz;
                        if (kz < 0 || kz > 2) continue;
#pragma unroll
                        for (int cy = 0; cy < 2; ++cy) {
                            const int ky = yi - cy;
                            if (ky < 0 || ky > 2) continue;
                            const int tg = (kz * 3 + ky) * 2 + xg;
                            acc[cz][cy] = __builtin_amdgcn_mfma_f32_16x16x32_bf16(
                                a, *(const bf16x8*)&B[tg], acc[cz][cy], 0, 0, 0);
                        }
                    }
                }
            }
        }
        const int co = cog * 16 + lm;
#pragma unroll
        for (int ip = 0; ip < 2; ++ip) {
            float m0 = fmaxf(fmaxf(acc[0][0][2 * ip], acc[0][1][2 * ip]),
                             fmaxf(acc[1][0][2 * ip], acc[1][1][2 * ip]));
            float m1 = fmaxf(fmaxf(acc[0][0][2 * ip + 1], acc[0][1][2 * ip + 1]),
                             fmaxf(acc[1][0][2 * ip + 1], acc[1][1][2 * ip + 1]));
            float o = fmaxf(fmaxf(m0, m1) * rmv + bia, 0.f);
            int px = x0 / 2 + lg * 2 + ip;
            X2[((((size_t)b * 24 + pz) * 24 + py) * 24 + px) * 32 + co] = f2bf(o);
        }
    }
}

// ---------------- generic MFMA conv (conv2/conv3): bias + pool + relu -> bf16 ch-last ----------------
template <int DIN, int DP, int CI, int NCH, int NCOG, int NPY, int NXS, int SPB, int NPZ>
__global__ __launch_bounds__(64, 3)
void convN_mfma(const unsigned short* __restrict__ X, const unsigned short* __restrict__ wp,
                const float* __restrict__ bias, unsigned short* __restrict__ Y, int COUT) {
    const int l = threadIdx.x, lm = l & 15, lg = l >> 4;
    const int s0 = blockIdx.x * SPB;
    const int r0 = s0 / (NPY * NXS);        // uniform in block (SPB | NPY*NXS)
    const int cog = r0 % NCOG;
    const int pz  = (r0 / NCOG) % NPZ;
    const int b   = r0 / (NCOG * NPZ);
    const float bia = bias[cog * 16 + lm];
    const unsigned short* Xb = X + (size_t)b * DIN * DIN * DIN * CI;
    const uint4* wp4 = (const uint4*)wp;
    const f32x4 z4 = {0.f, 0.f, 0.f, 0.f};
#pragma unroll 1
    for (int si = 0; si < SPB; ++si) {
        const int sid = s0 + si;
        const int xs = sid % NXS;
        const int py = (sid / NXS) % NPY;
        const int x0 = xs * 16;
        int xo[3];
#pragma unroll
        for (int kx = 0; kx < 3; ++kx) {
            int xin = x0 + kx + lm;
            if (xin > DIN - 1) xin = DIN - 1;     // garbage rows masked at store
            xo[kx] = xin * CI + lg * 8;
        }
        f32x4 acc[2][2];
#pragma unroll
        for (int cz = 0; cz < 2; ++cz)
#pragma unroll
            for (int cy = 0; cy < 2; ++cy) acc[cz][cy] = z4;
#pragma unroll 1
        for (int ch = 0; ch < NCH; ++ch) {
            uint4 B[27];
            const uint4* wpb = wp4 + ((size_t)cog * 27 * NCH + ch) * 64;
#pragma unroll
            for (int t = 0; t < 27; ++t) B[t] = wpb[(size_t)t * NCH * 64 + l];
            const unsigned short* Xc = Xb + ch * 32;
#pragma unroll
            for (int zi = 0; zi < 4; ++zi) {
                const int zin = 2 * pz + zi;
#pragma unroll
                for (int yi = 0; yi < 4; ++yi) {
                    const int yin = 2 * py + yi;
                    const unsigned short* rowb = Xc + (size_t)(zin * DIN + yin) * DIN * CI;
#pragma unroll
                    for (int kx = 0; kx < 3; ++kx) {
                        bf16x8 a = *(const bf16x8*)(rowb + xo[kx]);
#pragma unroll
                        for (int cz = 0; cz < 2; ++cz) {
                            const int kz = zi - cz;
                            if (kz < 0 || kz > 2) continue;
#pragma unroll
                            for (int cy = 0; cy < 2; ++cy) {
                                const int ky = yi - cy;
                                if (ky < 0 || ky > 2) continue;
                                const int tap = (kz * 3 + ky) * 3 + kx;
                                acc[cz][cy] = __builtin_amdgcn_mfma_f32_16x16x32_bf16(
                                    a, *(const bf16x8*)&B[tap], acc[cz][cy], 0, 0, 0);
                            }
                        }
                    }
                }
            }
        }
        const int co = cog * 16 + lm;
#pragma unroll
        for (int ip = 0; ip < 2; ++ip) {
            float m0 = fmaxf(fmaxf(acc[0][0][2 * ip], acc[0][1][2 * ip]),
                             fmaxf(acc[1][0][2 * ip], acc[1][1][2 * ip]));
            float m1 = fmaxf(fmaxf(acc[0][0][2 * ip + 1], acc[0][1][2 * ip + 1]),
                             fmaxf(acc[1][0][2 * ip + 1], acc[1][1][2 * ip + 1]));
            float o = fmaxf(fmaxf(m0, m1) + bia, 0.f);
            int px = x0 / 2 + lg * 2 + ip;
            if (px < DP)
                Y[((((size_t)b * DP + pz) * DP + py) * DP + px) * COUT + co] = f2bf(o);
        }
    }
}

// ---------------- conv4: channels-last bf16 in, fp32 weights; wave per (b,co) ----------------
__global__ void conv4_kernel(const unsigned short* __restrict__ X4, const float* __restrict__ w,
                             const float* __restrict__ bias, float* __restrict__ out) {
    int wid = (int)((blockIdx.x * blockDim.x + threadIdx.x) >> 6);
    int lane = threadIdx.x & 63;
    if (wid >= NB * 256) return;
    int b = wid >> 8, co = wid & 255;
    float acc[8];
#pragma unroll
    for (int i = 0; i < 8; ++i) acc[i] = 0.f;
    for (int half = 0; half < 2; ++half) {
        int ci = lane + half * 64;
        float win[64];
#pragma unroll
        for (int v = 0; v < 64; ++v)
            win[v] = __uint_as_float((unsigned)X4[((size_t)b * 64 + v) * 128 + ci] << 16);
        const float* wc = w + ((size_t)co * 128 + ci) * 27;
        float wr[27];
#pragma unroll
        for (int i = 0; i < 27; ++i) wr[i] = wc[i];
#pragma unroll
        for (int kz = 0; kz < 3; ++kz)
#pragma unroll
            for (int ky = 0; ky < 3; ++ky)
#pragma unroll
                for (int kx = 0; kx < 3; ++kx) {
                    float wv = wr[(kz * 3 + ky) * 3 + kx];
#pragma unroll
                    for (int oz = 0; oz < 2; ++oz)
#pragma unroll
                        for (int oy = 0; oy < 2; ++oy)
#pragma unroll
                            for (int ox = 0; ox < 2; ++ox)
                                acc[(oz * 2 + oy) * 2 + ox] =
                                    fmaf(wv, win[((oz + kz) * 4 + (oy + ky)) * 4 + ox + kx],
                                         acc[(oz * 2 + oy) * 2 + ox]);
                }
    }
#pragma unroll
    for (int o = 32; o; o >>= 1)
#pragma unroll
        for (int i = 0; i < 8; ++i) acc[i] += __shfl_xor(acc[i], o);
    if (lane == 0) {
        float m = acc[0];
#pragma unroll
        for (int i = 1; i < 8; ++i) m = fmaxf(m, acc[i]);
        out[(size_t)b * 256 + co] = fmaxf(m + bias[co], 0.f);
    }
}

// ---------------- FC head: (8,256) -> relu(128) -> 29 ----------------
__global__ void head_kernel(const float* __restrict__ v,
                            const float* __restrict__ fw1, const float* __restrict__ fb1,
                            const float* __restrict__ fw2, const float* __restrict__ fb2,
                            float* __restrict__ out) {
    int b = blockIdx.x, t = threadIdx.x;
    __shared__ float sv[256];
    __shared__ float s1[128];
    sv[t] = v[b * 256 + t];
    sv[t + 128] = v[b * 256 + t + 128];
    __syncthreads();
    float acc = fb1[t];
    const float* wr = fw1 + t * 256;
    for (int k = 0; k < 256; ++k) acc = fmaf(wr[k], sv[k], acc);
    s1[t] = fmaxf(acc, 0.f);
    __syncthreads();
    if (t < 29) {
        float a2 = fb2[t];
        const float* w2 = fw2 + t * 128;
        for (int k = 0; k < 128; ++k) a2 = fmaf(w2[k], s1[k], a2);
        out[b * 29 + t] = a2;
    }
}

extern "C" void kernel_launch(void* const* d_in, const int* in_sizes, int n_in,
                              void* d_out, int out_size, void* d_ws, size_t ws_size,
                              hipStream_t stream) {
    const float* x     = (const float*)d_in[0];
    const float* sigma = (const float*)d_in[1];
    const float* w1    = (const float*)d_in[2];
    const float* b1    = (const float*)d_in[3];
    const float* w2    = (const float*)d_in[4];
    const float* b2    = (const float*)d_in[5];
    const float* w3    = (const float*)d_in[6];
    const float* b3    = (const float*)d_in[7];
    const float* w4    = (const float*)d_in[8];
    const float* b4    = (const float*)d_in[9];
    const float* fw1   = (const float*)d_in[10];
    const float* fb1   = (const float*)d_in[11];
    const float* fw2   = (const float*)d_in[12];
    const float* fb2   = (const float*)d_in[13];
    float* out = (float*)d_out;

    // ---- workspace layout (~65.3 MB) ----
    float* A = (float*)d_ws;                                  // 6,000,000 f
    unsigned short* X1 = (unsigned short*)(A + NVOX);         // 16,000,064 ush (incl. pad)
    float* Bf = (float*)X1;                                   // blur tmp overlays X1 (dead before T1)
    unsigned short* X2  = X1 + 16000064;                      // 3,538,944
    unsigned short* X3  = X2 + 3538944;                       // 681,472
    unsigned short* X4  = X3 + 681472;                        // 65,536
    unsigned short* wp1 = X4 + 65536;                         // 18,432
    unsigned short* wp2 = wp1 + 18432;                        // 55,296
    unsigned short* wp3 = wp2 + 55296;                        // 221,184
    float* MT0 = (float*)(wp3 + 221184);                      // 6*50*52
    float* MT1 = MT0 + NE * 50 * MP;                          // 6*50*52
    float* mx  = MT1 + NE * 50 * MP;                          // 1
    float* v4  = mx + 1;                                      // 2048 f

    taps_kernel<<<1, 512, 0, stream>>>(sigma, MT0, MT1, mx);

    // separable blur: 3 per-plane 50x50 matmuls, M^T in LDS (scaled taps + max in last)
    blur_mm<2, false><<<NB * NE * 50, 256, 0, stream>>>(x,  A,  MT0, nullptr);
    blur_mm<1, false><<<NB * NE * 50, 256, 0, stream>>>(A,  Bf, MT0, nullptr);
    blur_mm<0, true> <<<NB * NE * 50, 256, 0, stream>>>(Bf, A,  MT1, mx);

    // channels-last bf16 conversion + weight fragment packing
    t1_kernel<<<400, 256, 0, stream>>>(A, X1);
    wprep1_kernel<<<36, 64, 0, stream>>>(w1, wp1);
    wprep_kernel<<<27, 256, 0, stream>>>(w2, wp2, 32, 1, 4);
    wprep_kernel<<<108, 256, 0, stream>>>(w3, wp3, 64, 2, 8);

    // conv1: MFMA shift-GEMM, dual-x-tap K packing
    conv1_mfma<<<3456, 64, 0, stream>>>(X1, wp1, b1, mx, X2);
    // conv2
    convN_mfma<24, 11, 32, 1, 4, 11, 2, 2, 11><<<3872, 64, 0, stream>>>(X2, wp2, b2, X3, 64);
    // conv3
    convN_mfma<11, 4, 64, 2, 8, 4, 1, 1, 4><<<1024, 64, 0, stream>>>(X3, wp3, b3, X4, 128);

    // conv4 (VALU, channels-last bf16 in) + head
    conv4_kernel<<<512, 256, 0, stream>>>(X4, w4, b4, v4);
    head_kernel<<<8, 128, 0, stream>>>(v4, fw1, fb1, fw2, fb2, out);
}

// Round 13
// 261.749 us; speedup vs baseline: 1.3365x; 1.3352x over previous
//
#include <hip/hip_runtime.h>
#include <math.h>

#define DIMX 50
#define KK   51
#define NE   6
#define NB   8
#define NVOX ((size_t)NB * NE * DIMX * DIMX * DIMX)  // 6,000,000

typedef short bf16x8 __attribute__((ext_vector_type(8)));
typedef float f32x4  __attribute__((ext_vector_type(4)));

__device__ __forceinline__ unsigned short f2bf(float f) {
    unsigned u = __float_as_uint(f);
    u += 0x7fffu + ((u >> 16) & 1u);      // RNE; inputs finite
    return (unsigned short)(u >> 16);
}
__device__ __forceinline__ float bf2f(unsigned short h) {
    return __uint_as_float((unsigned)h << 16);
}
// fragment-linear LDS offsets (ushort units)
// B-side: own=x(col), k: frag=((x>>4)*2+(k>>5)), lane=((k>>3)&3)*16+(x&15), j=k&7
__device__ __forceinline__ int offB(int x, int k) {
    return ((((x >> 4) * 2 + (k >> 5)) * 64 + ((k >> 3) & 3) * 16 + (x & 15)) << 3) + (k & 7);
}
// A-side: own=o(row), k: frag=((o>>4)*2+(k>>5)), lane=((k>>3)&3)*16+(o&15), j=k&7
__device__ __forceinline__ int offA(int o, int k) {
    return ((((o >> 4) * 2 + (k >> 5)) * 64 + ((k >> 3) & 3) * 16 + (o & 15)) << 3) + (k & 7);
}

// -------- taps + MFMA-fragment-packed blur matrices --------
// MA[hl][e][t][kc][l][j]: A-side frags of RAW taps (own=o, k=z), val=tap[z-o+25]
// MB[hl][e][t][kc][l][j]: B-side frags of SCALED taps (own=ox, k=x), val=stap[x-ox+25]
__global__ void taps_kernel(const float* __restrict__ sigma,
                            unsigned short* __restrict__ MA, unsigned short* __restrict__ MB,
                            float* __restrict__ maxval) {
    __shared__ float sg[NE * KK];
    __shared__ float sgs[NE * KK];
    __shared__ float ssum[NE];
    int t = threadIdx.x;
    if (t == 0) *maxval = 0.f;
    if (t < NE * KK) {
        int e = t / KK, i = t % KK;
        float d = (float)i - 25.0f;
        float var = sigma[e] * sigma[e];
        sg[t] = expf(-d * d / (2.f * var));
    }
    __syncthreads();
    if (t < NE) {
        float s = 0.f;
        for (int i = 0; i < KK; ++i) s += sg[t * KK + i];
        ssum[t] = s;
    }
    __syncthreads();
    if (t < NE * KK) {
        int e = t / KK;
        float S = 0.f;
        for (int e2 = 0; e2 < NE; ++e2) {
            float var2 = sigma[e2] * sigma[e2];
            float a2 = 1.f / (2.f * (float)M_PI * var2);
            float se = ssum[e2];
            S += a2 * se * se * se;
        }
        float var = sigma[e] * sigma[e];
        float a = 1.f / (2.f * (float)M_PI * var);
        sgs[t] = sg[t] * (a / S);
    }
    __syncthreads();
    const int TOT = 2 * 6 * 4 * 2 * 64 * 8;   // 49152 per matrix
    for (int i = t; i < 2 * TOT; i += 512) {
        int which = i / TOT;                   // 0=MA(raw) 1=MB(scaled)
        int r = i % TOT;
        int q = r;
        int j = q & 7; q >>= 3;
        int l = q & 63; q >>= 6;
        int kc = q & 1; q >>= 1;
        int tile = q & 3; q >>= 2;
        int e = q % 6; q /= 6;
        int hl = q;                            // 0=hi 1=lo
        int own = tile * 16 + (l & 15);
        int k   = kc * 32 + ((l >> 4) << 3) + j;
        float v = 0.f;
        if (own < 50 && k < 50) {
            int d = k - own + 25;
            if (d >= 0 && d < KK) v = (which == 0 ? sg : sgs)[e * KK + d];
        }
        unsigned short h = f2bf(v);
        unsigned short out = (hl == 0) ? h : f2bf(v - bf2f(h));
        (which == 0 ? MA : MB)[r] = out;
    }
}

// -------- K1: z-axis blur via MFMA, one (be,y) plane per 1-wave block --------
__global__ __launch_bounds__(64)
void blur_k1(const float* __restrict__ in, float* __restrict__ W1,
             const unsigned short* __restrict__ MA) {
    __shared__ unsigned short Bhi[4096], Blo[4096];
    const int l = threadIdx.x, lm = l & 15, lg = l >> 4;
    const int y = blockIdx.x % 50, be = blockIdx.x / 50, e = be % 6;
    const float* pb = in + (size_t)be * 125000 + y * 50;
#pragma unroll 8
    for (int z = 0; z < 64; ++z) {
        float v = (z < 50 && l < 50) ? pb[(size_t)z * 2500 + l] : 0.f;
        unsigned short h = f2bf(v);
        unsigned short lo = f2bf(v - bf2f(h));
        int off = offB(l, z);
        Bhi[off] = h; Blo[off] = lo;
    }
    __builtin_amdgcn_wave_barrier();
    asm volatile("s_waitcnt lgkmcnt(0)" ::: "memory");
    __builtin_amdgcn_sched_barrier(0);
    float* ob = W1 + (size_t)be * 125000 + y * 50;
    const f32x4 z4 = {0.f, 0.f, 0.f, 0.f};
#pragma unroll 1
    for (int ozt = 0; ozt < 4; ++ozt) {
        bf16x8 Ah[2], Al[2];
#pragma unroll
        for (int kc = 0; kc < 2; ++kc) {
            Ah[kc] = *(const bf16x8*)(MA + (((size_t)(0 * 6 + e) * 4 + ozt) * 2 + kc) * 512 + l * 8);
            Al[kc] = *(const bf16x8*)(MA + (((size_t)(1 * 6 + e) * 4 + ozt) * 2 + kc) * 512 + l * 8);
        }
#pragma unroll
        for (int xt = 0; xt < 4; ++xt) {
            f32x4 acc = z4;
#pragma unroll
            for (int kc = 0; kc < 2; ++kc) {
                bf16x8 bh = *(const bf16x8*)(Bhi + ((xt * 2 + kc) * 64 + l) * 8);
                bf16x8 bl = *(const bf16x8*)(Blo + ((xt * 2 + kc) * 64 + l) * 8);
                acc = __builtin_amdgcn_mfma_f32_16x16x32_bf16(Ah[kc], bh, acc, 0, 0, 0);
                acc = __builtin_amdgcn_mfma_f32_16x16x32_bf16(Ah[kc], bl, acc, 0, 0, 0);
                acc = __builtin_amdgcn_mfma_f32_16x16x32_bf16(Al[kc], bh, acc, 0, 0, 0);
            }
            int x = xt * 16 + lm;
            if (x < 50) {
#pragma unroll
                for (int i = 0; i < 4; ++i) {
                    int oz = ozt * 16 + lg * 4 + i;
                    if (oz < 50) ob[(size_t)oz * 2500 + x] = acc[i];
                }
            }
        }
    }
}

// -------- K2: fused y-blur + x-blur(scaled) + global max; in-place on W1 --------
__global__ __launch_bounds__(64)
void blur_k2(float* __restrict__ W1, const unsigned short* __restrict__ MA,
             const unsigned short* __restrict__ MB, float* __restrict__ maxval) {
    __shared__ unsigned short Bhi[4096], Blo[4096];
    __shared__ unsigned short Qhi[4096], Qlo[4096];
    const int l = threadIdx.x, lm = l & 15, lg = l >> 4;
    const int z = blockIdx.x % 50, be = blockIdx.x / 50, e = be % 6;
    float* pb = W1 + (size_t)be * 125000 + (size_t)z * 2500;
#pragma unroll 8
    for (int y = 0; y < 64; ++y) {
        float v = (y < 50 && l < 50) ? pb[y * 50 + l] : 0.f;
        unsigned short h = f2bf(v);
        unsigned short lo = f2bf(v - bf2f(h));
        int off = offB(l, y);   // own=x(col)=l, k=y
        Bhi[off] = h; Blo[off] = lo;
    }
    __builtin_amdgcn_wave_barrier();
    asm volatile("s_waitcnt lgkmcnt(0)" ::: "memory");
    __builtin_amdgcn_sched_barrier(0);
    const f32x4 z4 = {0.f, 0.f, 0.f, 0.f};
    // step1: Q[oy][x] = sum_y M0[oy][y] P[y][x]
#pragma unroll 1
    for (int oyt = 0; oyt < 4; ++oyt) {
        bf16x8 Ah[2], Al[2];
#pragma unroll
        for (int kc = 0; kc < 2; ++kc) {
            Ah[kc] = *(const bf16x8*)(MA + (((size_t)(0 * 6 + e) * 4 + oyt) * 2 + kc) * 512 + l * 8);
            Al[kc] = *(const bf16x8*)(MA + (((size_t)(1 * 6 + e) * 4 + oyt) * 2 + kc) * 512 + l * 8);
        }
#pragma unroll
        for (int xt = 0; xt < 4; ++xt) {
            f32x4 acc = z4;
#pragma unroll
            for (int kc = 0; kc < 2; ++kc) {
                bf16x8 bh = *(const bf16x8*)(Bhi + ((xt * 2 + kc) * 64 + l) * 8);
                bf16x8 bl = *(const bf16x8*)(Blo + ((xt * 2 + kc) * 64 + l) * 8);
                acc = __builtin_amdgcn_mfma_f32_16x16x32_bf16(Ah[kc], bh, acc, 0, 0, 0);
                acc = __builtin_amdgcn_mfma_f32_16x16x32_bf16(Ah[kc], bl, acc, 0, 0, 0);
                acc = __builtin_amdgcn_mfma_f32_16x16x32_bf16(Al[kc], bh, acc, 0, 0, 0);
            }
#pragma unroll
            for (int i = 0; i < 4; ++i) {
                int oy = oyt * 16 + lg * 4 + i;
                int x  = xt * 16 + lm;
                float qv = acc[i];
                unsigned short h = f2bf(qv);
                unsigned short lo = f2bf(qv - bf2f(h));
                int off = offA(oy, x);   // own=oy(row), k=x
                Qhi[off] = h; Qlo[off] = lo;
            }
        }
    }
    __builtin_amdgcn_wave_barrier();
    asm volatile("s_waitcnt lgkmcnt(0)" ::: "memory");
    __builtin_amdgcn_sched_barrier(0);
    // step2: R[oy][ox] = sum_x Q[oy][x] M1[ox][x]   (scaled taps), + max, in-place store
    float mmax = 0.f;
#pragma unroll 1
    for (int oyt = 0; oyt < 4; ++oyt) {
        bf16x8 Qh[2], Ql[2];
#pragma unroll
        for (int kc = 0; kc < 2; ++kc) {
            Qh[kc] = *(const bf16x8*)(Qhi + ((oyt * 2 + kc) * 64 + l) * 8);
            Ql[kc] = *(const bf16x8*)(Qlo + ((oyt * 2 + kc) * 64 + l) * 8);
        }
#pragma unroll
        for (int oxt = 0; oxt < 4; ++oxt) {
            f32x4 acc = z4;
#pragma unroll
            for (int kc = 0; kc < 2; ++kc) {
                bf16x8 mh = *(const bf16x8*)(MB + (((size_t)(0 * 6 + e) * 4 + oxt) * 2 + kc) * 512 + l * 8);
                bf16x8 ml = *(const bf16x8*)(MB + (((size_t)(1 * 6 + e) * 4 + oxt) * 2 + kc) * 512 + l * 8);
                acc = __builtin_amdgcn_mfma_f32_16x16x32_bf16(Qh[kc], mh, acc, 0, 0, 0);
                acc = __builtin_amdgcn_mfma_f32_16x16x32_bf16(Qh[kc], ml, acc, 0, 0, 0);
                acc = __builtin_amdgcn_mfma_f32_16x16x32_bf16(Ql[kc], mh, acc, 0, 0, 0);
            }
            int ox = oxt * 16 + lm;
            if (ox < 50) {
#pragma unroll
                for (int i = 0; i < 4; ++i) {
                    int oy = oyt * 16 + lg * 4 + i;
                    if (oy < 50) {
                        float r = acc[i];
                        pb[oy * 50 + ox] = r;
                        mmax = fmaxf(mmax, r);
                    }
                }
            }
        }
    }
    for (int o = 32; o; o >>= 1) mmax = fmaxf(mmax, __shfl_xor(mmax, o));
    if (l == 0) atomicMax((int*)maxval, __float_as_int(mmax));
}

// ---------------- T1: blurred fp32 [b*6+e][z][y][x] -> X1 bf16 8-pack [b][z][y][x][8] ----------------
__global__ __launch_bounds__(256)
void t1_kernel(const float* __restrict__ A, unsigned short* __restrict__ X1) {
    const int z = blockIdx.x % 50, b = blockIdx.x / 50;
    const float* ab = A + (size_t)b * 6 * 125000 + (size_t)z * 2500;
    unsigned short* xb = X1 + ((size_t)b * 125000 + (size_t)z * 2500) * 8;
    for (int i = threadIdx.x; i < 2500; i += 256) {
        unsigned short v[6];
#pragma unroll
        for (int e = 0; e < 6; ++e) v[e] = f2bf(ab[(size_t)e * 125000 + i]);
        uint4 q;
        q.x = v[0] | ((unsigned)v[1] << 16);
        q.y = v[2] | ((unsigned)v[3] << 16);
        q.z = v[4] | ((unsigned)v[5] << 16);
        q.w = 0u;
        *(uint4*)(xb + (size_t)i * 8) = q;
    }
}

// ---------------- weight prep: generic B-fragment pack [cog][tap][ch][lane][8] ----------------
__global__ void wprep_kernel(const float* __restrict__ W, unsigned short* __restrict__ out,
                             int CIN, int NCH, int NCOG) {
    int idx = blockIdx.x * 256 + threadIdx.x;
    int total = NCOG * 27 * NCH * 64;
    if (idx >= total) return;
    int l = idx & 63;
    int r = idx >> 6;
    int ch = r % NCH; r /= NCH;
    int tap = r % 27;
    int cog = r / 27;
    int co = cog * 16 + (l & 15);
    unsigned short v[8];
#pragma unroll
    for (int j = 0; j < 8; ++j) {
        int ci = ch * 32 + (l >> 4) * 8 + j;
        v[j] = (ci < CIN) ? f2bf(W[((size_t)co * CIN + ci) * 27 + tap]) : (unsigned short)0;
    }
    uint4 q;
    q.x = v[0] | ((unsigned)v[1] << 16);
    q.y = v[2] | ((unsigned)v[3] << 16);
    q.z = v[4] | ((unsigned)v[5] << 16);
    q.w = v[6] | ((unsigned)v[7] << 16);
    ((uint4*)out)[idx] = q;
}

// ---------------- conv1 weight prep: 4-xsel packing [cog][9][lane][8] ----------------
// k = xsel*8 + ci; xsel(=l>>4): 0,1,2 -> kx; 3 -> zero. ci(=j): 0..5 real.
__global__ void wprep1_kernel(const float* __restrict__ W, unsigned short* __restrict__ out) {
    int idx = blockIdx.x * 64 + threadIdx.x;
    if (idx >= 2 * 9 * 64) return;
    int l = idx & 63;
    int r = idx >> 6;
    int tg = r % 9;           // kz*3+ky
    int cog = r / 9;
    int xsel = l >> 4;
    int co = cog * 16 + (l & 15);
    unsigned short v[8];
#pragma unroll
    for (int j = 0; j < 8; ++j) {
        float wv = 0.f;
        if (j < 6 && xsel < 3) wv = W[((size_t)co * 6 + j) * 27 + tg * 3 + xsel];
        v[j] = f2bf(wv);
    }
    uint4 q;
    q.x = v[0] | ((unsigned)v[1] << 16);
    q.y = v[2] | ((unsigned)v[3] << 16);
    q.z = v[4] | ((unsigned)v[5] << 16);
    q.w = v[6] | ((unsigned)v[7] << 16);
    ((uint4*)out)[idx] = q;
}

// ---------------- conv1 MFMA: X1[50^3][8] -> X2[24^3][32], /max + bias + pool + relu ----------------
// K=32 = 4 xsel x 8 ci; one mfma per (zi,yi); 36 mfma + 16 A-loads per strip. XCD-swizzled.
__global__ __launch_bounds__(64, 3)
void conv1_mfma(const unsigned short* __restrict__ X8, const unsigned short* __restrict__ wp1,
                const float* __restrict__ bias, const float* __restrict__ maxval,
                unsigned short* __restrict__ X2) {
    const int l = threadIdx.x, lm = l & 15, lg = l >> 4;
    const int q = (int)(gridDim.x >> 3);
    const int bid = ((int)blockIdx.x & 7) * q + ((int)blockIdx.x >> 3);
    const int s0 = bid * 8;
    const int r0 = s0 / 72;                 // uniform in block (8 | 72)
    const int cog = r0 % 2;
    const int pz  = (r0 / 2) % 24;
    const int b   = r0 / 48;
    uint4 B9[9];
    const uint4* wpb = (const uint4*)wp1 + cog * 9 * 64;
#pragma unroll
    for (int t = 0; t < 9; ++t) B9[t] = wpb[t * 64 + l];
    const float rmv = 1.0f / (*maxval);
    const float bia = bias[cog * 16 + lm];
    const unsigned short* Xb = X8 + (size_t)b * 125000 * 8;
    const f32x4 z4 = {0.f, 0.f, 0.f, 0.f};
#pragma unroll 1
    for (int si = 0; si < 8; ++si) {
        const int sid = s0 + si;
        const int xs = sid % 3;
        const int py = (sid / 3) % 24;
        const int x0 = xs * 16;
        f32x4 acc[2][2];
#pragma unroll
        for (int cz = 0; cz < 2; ++cz)
#pragma unroll
            for (int cy = 0; cy < 2; ++cy) acc[cz][cy] = z4;
#pragma unroll
        for (int zi = 0; zi < 4; ++zi) {
            const int zin = 2 * pz + zi;
#pragma unroll
            for (int yi = 0; yi < 4; ++yi) {
                const int yin = 2 * py + yi;
                const unsigned short* rowb = Xb + (size_t)(zin * 50 + yin) * 50 * 8;
                bf16x8 a = *(const bf16x8*)(rowb + (x0 + lm + lg) * 8);
#pragma unroll
                for (int cz = 0; cz < 2; ++cz) {
                    const int kz = zi - cz;
                    if (kz < 0 || kz > 2) continue;
#pragma unroll
                    for (int cy = 0; cy < 2; ++cy) {
                        const int ky = yi - cy;
                        if (ky < 0 || ky > 2) continue;
                        acc[cz][cy] = __builtin_amdgcn_mfma_f32_16x16x32_bf16(
                            a, *(const bf16x8*)&B9[kz * 3 + ky], acc[cz][cy], 0, 0, 0);
                    }
                }
            }
        }
        const int co = cog * 16 + lm;
#pragma unroll
        for (int ip = 0; ip < 2; ++ip) {
            float m0 = fmaxf(fmaxf(acc[0][0][2 * ip], acc[0][1][2 * ip]),
                             fmaxf(acc[1][0][2 * ip], acc[1][1][2 * ip]));
            float m1 = fmaxf(fmaxf(acc[0][0][2 * ip + 1], acc[0][1][2 * ip + 1]),
                             fmaxf(acc[1][0][2 * ip + 1], acc[1][1][2 * ip + 1]));
            float o = fmaxf(fmaxf(m0, m1) * rmv + bia, 0.f);
            int px = x0 / 2 + lg * 2 + ip;
            X2[((((size_t)b * 24 + pz) * 24 + py) * 24 + px) * 32 + co] = f2bf(o);
        }
    }
}

// ---------------- generic MFMA conv (conv2/conv3): bias + pool + relu -> bf16 ch-last ----------------
template <int DIN, int DP, int CI, int NCH, int NCOG, int NPY, int NXS, int SPB, int NPZ>
__global__ __launch_bounds__(64, 3)
void convN_mfma(const unsigned short* __restrict__ X, const unsigned short* __restrict__ wp,
                const float* __restrict__ bias, unsigned short* __restrict__ Y, int COUT) {
    const int l = threadIdx.x, lm = l & 15, lg = l >> 4;
    const int qq = (int)(gridDim.x >> 3);
    const int bid = ((int)blockIdx.x & 7) * qq + ((int)blockIdx.x >> 3);
    const int s0 = bid * SPB;
    const int r0 = s0 / (NPY * NXS);        // uniform in block
    const int cog = r0 % NCOG;
    const int pz  = (r0 / NCOG) % NPZ;
    const int b   = r0 / (NCOG * NPZ);
    const float bia = bias[cog * 16 + lm];
    const unsigned short* Xb = X + (size_t)b * DIN * DIN * DIN * CI;
    const uint4* wp4 = (const uint4*)wp;
    const f32x4 z4 = {0.f, 0.f, 0.f, 0.f};
#pragma unroll 1
    for (int si = 0; si < SPB; ++si) {
        const int sid = s0 + si;
        const int xs = sid % NXS;
        const int py = (sid / NXS) % NPY;
        const int x0 = xs * 16;
        int xo[3];
#pragma unroll
        for (int kx = 0; kx < 3; ++kx) {
            int xin = x0 + kx + lm;
            if (xin > DIN - 1) xin = DIN - 1;     // garbage rows masked at store
            xo[kx] = xin * CI + lg * 8;
        }
        f32x4 acc[2][2];
#pragma unroll
        for (int cz = 0; cz < 2; ++cz)
#pragma unroll
            for (int cy = 0; cy < 2; ++cy) acc[cz][cy] = z4;
#pragma unroll 1
        for (int ch = 0; ch < NCH; ++ch) {
            uint4 B[27];
            const uint4* wpb = wp4 + ((size_t)cog * 27 * NCH + ch) * 64;
#pragma unroll
            for (int t = 0; t < 27; ++t) B[t] = wpb[(size_t)t * NCH * 64 + l];
            const unsigned short* Xc = Xb + ch * 32;
#pragma unroll
            for (int zi = 0; zi < 4; ++zi) {
                const int zin = 2 * pz + zi;
#pragma unroll
                for (int yi = 0; yi < 4; ++yi) {
                    const int yin = 2 * py + yi;
                    const unsigned short* rowb = Xc + (size_t)(zin * DIN + yin) * DIN * CI;
#pragma unroll
                    for (int kx = 0; kx < 3; ++kx) {
                        bf16x8 a = *(const bf16x8*)(rowb + xo[kx]);
#pragma unroll
                        for (int cz = 0; cz < 2; ++cz) {
                            const int kz = zi - cz;
                            if (kz < 0 || kz > 2) continue;
#pragma unroll
                            for (int cy = 0; cy < 2; ++cy) {
                                const int ky = yi - cy;
                                if (ky < 0 || ky > 2) continue;
                                const int tap = (kz * 3 + ky) * 3 + kx;
                                acc[cz][cy] = __builtin_amdgcn_mfma_f32_16x16x32_bf16(
                                    a, *(const bf16x8*)&B[tap], acc[cz][cy], 0, 0, 0);
                            }
                        }
                    }
                }
            }
        }
        const int co = cog * 16 + lm;
#pragma unroll
        for (int ip = 0; ip < 2; ++ip) {
            float m0 = fmaxf(fmaxf(acc[0][0][2 * ip], acc[0][1][2 * ip]),
                             fmaxf(acc[1][0][2 * ip], acc[1][1][2 * ip]));
            float m1 = fmaxf(fmaxf(acc[0][0][2 * ip + 1], acc[0][1][2 * ip + 1]),
                             fmaxf(acc[1][0][2 * ip + 1], acc[1][1][2 * ip + 1]));
            float o = fmaxf(fmaxf(m0, m1) + bia, 0.f);
            int px = x0 / 2 + lg * 2 + ip;
            if (px < DP)
                Y[((((size_t)b * DP + pz) * DP + py) * DP + px) * COUT + co] = f2bf(o);
        }
    }
}

// ---------------- conv4: channels-last bf16 in, fp32 weights; wave per (b,co) ----------------
__global__ void conv4_kernel(const unsigned short* __restrict__ X4, const float* __restrict__ w,
                             const float* __restrict__ bias, float* __restrict__ out) {
    int wid = (int)((blockIdx.x * blockDim.x + threadIdx.x) >> 6);
    int lane = threadIdx.x & 63;
    if (wid >= NB * 256) return;
    int b = wid >> 8, co = wid & 255;
    float acc[8];
#pragma unroll
    for (int i = 0; i < 8; ++i) acc[i] = 0.f;
    for (int half = 0; half < 2; ++half) {
        int ci = lane + half * 64;
        float win[64];
#pragma unroll
        for (int v = 0; v < 64; ++v)
            win[v] = bf2f(X4[((size_t)b * 64 + v) * 128 + ci]);
        const float* wc = w + ((size_t)co * 128 + ci) * 27;
        float wr[27];
#pragma unroll
        for (int i = 0; i < 27; ++i) wr[i] = wc[i];
#pragma unroll
        for (int kz = 0; kz < 3; ++kz)
#pragma unroll
            for (int ky = 0; ky < 3; ++ky)
#pragma unroll
                for (int kx = 0; kx < 3; ++kx) {
                    float wv = wr[(kz * 3 + ky) * 3 + kx];
#pragma unroll
                    for (int oz = 0; oz < 2; ++oz)
#pragma unroll
                        for (int oy = 0; oy < 2; ++oy)
#pragma unroll
                            for (int ox = 0; ox < 2; ++ox)
                                acc[(oz * 2 + oy) * 2 + ox] =
                                    fmaf(wv, win[((oz + kz) * 4 + (oy + ky)) * 4 + ox + kx],
                                         acc[(oz * 2 + oy) * 2 + ox]);
                }
    }
#pragma unroll
    for (int o = 32; o; o >>= 1)
#pragma unroll
        for (int i = 0; i < 8; ++i) acc[i] += __shfl_xor(acc[i], o);
    if (lane == 0) {
        float m = acc[0];
#pragma unroll
        for (int i = 1; i < 8; ++i) m = fmaxf(m, acc[i]);
        out[(size_t)b * 256 + co] = fmaxf(m + bias[co], 0.f);
    }
}

// ---------------- FC head: (8,256) -> relu(128) -> 29 ----------------
__global__ void head_kernel(const float* __restrict__ v,
                            const float* __restrict__ fw1, const float* __restrict__ fb1,
                            const float* __restrict__ fw2, const float* __restrict__ fb2,
                            float* __restrict__ out) {
    int b = blockIdx.x, t = threadIdx.x;
    __shared__ float sv[256];
    __shared__ float s1[128];
    sv[t] = v[b * 256 + t];
    sv[t + 128] = v[b * 256 + t + 128];
    __syncthreads();
    float acc = fb1[t];
    const float* wr = fw1 + t * 256;
    for (int k = 0; k < 256; ++k) acc = fmaf(wr[k], sv[k], acc);
    s1[t] = fmaxf(acc, 0.f);
    __syncthreads();
    if (t < 29) {
        float a2 = fb2[t];
        const float* w2 = fw2 + t * 128;
        for (int k = 0; k < 128; ++k) a2 = fmaf(w2[k], s1[k], a2);
        out[b * 29 + t] = a2;
    }
}

extern "C" void kernel_launch(void* const* d_in, const int* in_sizes, int n_in,
                              void* d_out, int out_size, void* d_ws, size_t ws_size,
                              hipStream_t stream) {
    const float* x     = (const float*)d_in[0];
    const float* sigma = (const float*)d_in[1];
    const float* w1    = (const float*)d_in[2];
    const float* b1    = (const float*)d_in[3];
    const float* w2    = (const float*)d_in[4];
    const float* b2    = (const float*)d_in[5];
    const float* w3    = (const float*)d_in[6];
    const float* b3    = (const float*)d_in[7];
    const float* w4    = (const float*)d_in[8];
    const float* b4    = (const float*)d_in[9];
    const float* fw1   = (const float*)d_in[10];
    const float* fb1   = (const float*)d_in[11];
    const float* fw2   = (const float*)d_in[12];
    const float* fb2   = (const float*)d_in[13];
    float* out = (float*)d_out;

    // ---- workspace layout (~50 MB) ----
    float* W1 = (float*)d_ws;                                 // 6,000,000 f
    unsigned short* X1  = (unsigned short*)(W1 + NVOX);       // 8,000,064
    unsigned short* X2  = X1 + 8000064;                       // 3,538,944
    unsigned short* X3  = X2 + 3538944;                       // 681,472
    unsigned short* X4  = X3 + 681472;                        // 65,536
    unsigned short* wp1 = X4 + 65536;                         // 9,216
    unsigned short* wp2 = wp1 + 9216;                         // 55,296
    unsigned short* wp3 = wp2 + 55296;                        // 221,184
    unsigned short* MA  = wp3 + 221184;                       // 49,152
    unsigned short* MB  = MA + 49152;                         // 49,152
    float* mx = (float*)(MB + 49152);                         // 1
    float* v4 = mx + 1;                                       // 2,048 f

    taps_kernel<<<1, 512, 0, stream>>>(sigma, MA, MB, mx);

    // blur: K1 (z-axis) then fused K2 (y+x axes, scaled taps, global max), in-place
    blur_k1<<<NB * NE * 50, 64, 0, stream>>>(x, W1, MA);
    blur_k2<<<NB * NE * 50, 64, 0, stream>>>(W1, MA, MB, mx);

    // channels-last bf16 (8-pack) + weight fragment packing
    t1_kernel<<<400, 256, 0, stream>>>(W1, X1);
    wprep1_kernel<<<18, 64, 0, stream>>>(w1, wp1);
    wprep_kernel<<<27, 256, 0, stream>>>(w2, wp2, 32, 1, 4);
    wprep_kernel<<<108, 256, 0, stream>>>(w3, wp3, 64, 2, 8);

    // conv1: 4-xsel K-packing, XCD-swizzled
    conv1_mfma<<<3456, 64, 0, stream>>>(X1, wp1, b1, mx, X2);
    // conv2 / conv3 (XCD-swizzled inside)
    convN_mfma<24, 11, 32, 1, 4, 11, 2, 2, 11><<<3872, 64, 0, stream>>>(X2, wp2, b2, X3, 64);
    convN_mfma<11, 4, 64, 2, 8, 4, 1, 1, 4><<<1024, 64, 0, stream>>>(X3, wp3, b3, X4, 128);

    // conv4 (VALU, channels-last bf16 in) + head
    conv4_kernel<<<512, 256, 0, stream>>>(X4, w4, b4, v4);
    head_kernel<<<8, 128, 0, stream>>>(v4, fw1, fb1, fw2, fb2, out);
}

// Round 14
// 212.247 us; speedup vs baseline: 1.6482x; 1.2332x over previous
//
#include <hip/hip_runtime.h>
#include <math.h>

#define DIMX 50
#define KK   51
#define NE   6
#define NB   8
#define NVOX ((size_t)NB * NE * DIMX * DIMX * DIMX)  // 6,000,000

typedef short bf16x8 __attribute__((ext_vector_type(8)));
typedef float f32x4  __attribute__((ext_vector_type(4)));

__device__ __forceinline__ unsigned short f2bf(float f) {
    unsigned u = __float_as_uint(f);
    u += 0x7fffu + ((u >> 16) & 1u);      // RNE; inputs finite
    return (unsigned short)(u >> 16);
}
__device__ __forceinline__ float bf2f(unsigned short h) {
    return __uint_as_float((unsigned)h << 16);
}
__device__ __forceinline__ uint4 pack8(const unsigned short v[8]) {
    uint4 q;
    q.x = v[0] | ((unsigned)v[1] << 16);
    q.y = v[2] | ((unsigned)v[3] << 16);
    q.z = v[4] | ((unsigned)v[5] << 16);
    q.w = v[6] | ((unsigned)v[7] << 16);
    return q;
}
// A-side fragment-linear offset: own=o(row), k; frag=((o>>4)*2+(k>>5)), lane=((k>>3)&3)*16+(o&15)
__device__ __forceinline__ int offA(int o, int k) {
    return ((((o >> 4) * 2 + (k >> 5)) * 64 + ((k >> 3) & 3) * 16 + (o & 15)) << 3) + (k & 7);
}

// -------- taps + MFMA-fragment-packed blur matrices --------
// MA[hl][e][t][kc][l][j]: A-side frags of RAW taps (own=o, k=z), val=tap[z-o+25]
// MB[hl][e][t][kc][l][j]: B-side frags of SCALED taps (own=ox, k=x), val=stap[x-ox+25]
__global__ void taps_kernel(const float* __restrict__ sigma,
                            unsigned short* __restrict__ MA, unsigned short* __restrict__ MB,
                            float* __restrict__ maxval) {
    __shared__ float sg[NE * KK];
    __shared__ float sgs[NE * KK];
    __shared__ float ssum[NE];
    int t = threadIdx.x;
    if (t == 0) *maxval = 0.f;
    if (t < NE * KK) {
        int e = t / KK, i = t % KK;
        float d = (float)i - 25.0f;
        float var = sigma[e] * sigma[e];
        sg[t] = expf(-d * d / (2.f * var));
    }
    __syncthreads();
    if (t < NE) {
        float s = 0.f;
        for (int i = 0; i < KK; ++i) s += sg[t * KK + i];
        ssum[t] = s;
    }
    __syncthreads();
    if (t < NE * KK) {
        int e = t / KK;
        float S = 0.f;
        for (int e2 = 0; e2 < NE; ++e2) {
            float var2 = sigma[e2] * sigma[e2];
            float a2 = 1.f / (2.f * (float)M_PI * var2);
            float se = ssum[e2];
            S += a2 * se * se * se;
        }
        float var = sigma[e] * sigma[e];
        float a = 1.f / (2.f * (float)M_PI * var);
        sgs[t] = sg[t] * (a / S);
    }
    __syncthreads();
    const int TOT = 2 * 6 * 4 * 2 * 64 * 8;   // 49152 per matrix
    for (int i = t; i < 2 * TOT; i += 512) {
        int which = i / TOT;                   // 0=MA(raw) 1=MB(scaled)
        int r = i % TOT;
        int q = r;
        int j = q & 7; q >>= 3;
        int l = q & 63; q >>= 6;
        int kc = q & 1; q >>= 1;
        int tile = q & 3; q >>= 2;
        int e = q % 6; q /= 6;
        int hl = q;                            // 0=hi 1=lo
        int own = tile * 16 + (l & 15);
        int k   = kc * 32 + ((l >> 4) << 3) + j;
        float v = 0.f;
        if (own < 50 && k < 50) {
            int d = k - own + 25;
            if (d >= 0 && d < KK) v = (which == 0 ? sg : sgs)[e * KK + d];
        }
        unsigned short h = f2bf(v);
        unsigned short out = (hl == 0) ? h : f2bf(v - bf2f(h));
        (which == 0 ? MA : MB)[r] = out;
    }
}

// -------- K1: z-axis blur via MFMA, one (be,y) plane per 1-wave block --------
// Staging: fragment-direct — lane l gathers its own 8 k-values, one b128 write per
// fragment (conflict-free, contiguous).
__global__ __launch_bounds__(64)
void blur_k1(const float* __restrict__ in, float* __restrict__ W1,
             const unsigned short* __restrict__ MA) {
    __shared__ unsigned short Bhi[4096], Blo[4096];
    const int l = threadIdx.x, lm = l & 15, lg = l >> 4;
    const int y = blockIdx.x % 50, be = blockIdx.x / 50, e = be % 6;
    const float* pb = in + (size_t)be * 125000 + y * 50;
#pragma unroll
    for (int xt = 0; xt < 4; ++xt)
#pragma unroll
        for (int kc = 0; kc < 2; ++kc) {
            const int xx = xt * 16 + lm;
            unsigned short vh[8], vl[8];
#pragma unroll
            for (int j = 0; j < 8; ++j) {
                int z = kc * 32 + lg * 8 + j;
                float v = (z < 50 && xx < 50) ? pb[(size_t)z * 2500 + xx] : 0.f;
                unsigned short h = f2bf(v);
                vh[j] = h; vl[j] = f2bf(v - bf2f(h));
            }
            const int T = xt * 2 + kc;
            *(uint4*)(Bhi + (T * 64 + l) * 8) = pack8(vh);
            *(uint4*)(Blo + (T * 64 + l) * 8) = pack8(vl);
        }
    __builtin_amdgcn_wave_barrier();
    asm volatile("s_waitcnt lgkmcnt(0)" ::: "memory");
    __builtin_amdgcn_sched_barrier(0);
    float* ob = W1 + (size_t)be * 125000 + y * 50;
    const f32x4 z4 = {0.f, 0.f, 0.f, 0.f};
#pragma unroll 1
    for (int ozt = 0; ozt < 4; ++ozt) {
        bf16x8 Ah[2], Al[2];
#pragma unroll
        for (int kc = 0; kc < 2; ++kc) {
            Ah[kc] = *(const bf16x8*)(MA + (((size_t)(0 * 6 + e) * 4 + ozt) * 2 + kc) * 512 + l * 8);
            Al[kc] = *(const bf16x8*)(MA + (((size_t)(1 * 6 + e) * 4 + ozt) * 2 + kc) * 512 + l * 8);
        }
#pragma unroll
        for (int xt = 0; xt < 4; ++xt) {
            f32x4 acc = z4;
#pragma unroll
            for (int kc = 0; kc < 2; ++kc) {
                bf16x8 bh = *(const bf16x8*)(Bhi + ((xt * 2 + kc) * 64 + l) * 8);
                bf16x8 bl = *(const bf16x8*)(Blo + ((xt * 2 + kc) * 64 + l) * 8);
                acc = __builtin_amdgcn_mfma_f32_16x16x32_bf16(Ah[kc], bh, acc, 0, 0, 0);
                acc = __builtin_amdgcn_mfma_f32_16x16x32_bf16(Ah[kc], bl, acc, 0, 0, 0);
                acc = __builtin_amdgcn_mfma_f32_16x16x32_bf16(Al[kc], bh, acc, 0, 0, 0);
            }
            int xx = xt * 16 + lm;
            if (xx < 50) {
#pragma unroll
                for (int i = 0; i < 4; ++i) {
                    int oz = ozt * 16 + lg * 4 + i;
                    if (oz < 50) ob[(size_t)oz * 2500 + xx] = acc[i];
                }
            }
        }
    }
}

// -------- K2: fused y-blur + x-blur(scaled) + global max; in-place on W1 --------
// Step1 accumulates all 16 tiles in registers; Q then overwrites the B LDS buffers
// (16 KB total -> ~10 blocks/CU).
__global__ __launch_bounds__(64)
void blur_k2(float* __restrict__ W1, const unsigned short* __restrict__ MA,
             const unsigned short* __restrict__ MB, float* __restrict__ maxval) {
    __shared__ unsigned short Bhi[4096], Blo[4096];
    const int l = threadIdx.x, lm = l & 15, lg = l >> 4;
    const int z = blockIdx.x % 50, be = blockIdx.x / 50, e = be % 6;
    float* pb = W1 + (size_t)be * 125000 + (size_t)z * 2500;
    // staging: fragment-direct, conflict-free b128 writes
#pragma unroll
    for (int xt = 0; xt < 4; ++xt)
#pragma unroll
        for (int kc = 0; kc < 2; ++kc) {
            const int xx = xt * 16 + lm;
            unsigned short vh[8], vl[8];
#pragma unroll
            for (int j = 0; j < 8; ++j) {
                int yy = kc * 32 + lg * 8 + j;
                float v = (yy < 50 && xx < 50) ? pb[yy * 50 + xx] : 0.f;
                unsigned short h = f2bf(v);
                vh[j] = h; vl[j] = f2bf(v - bf2f(h));
            }
            const int T = xt * 2 + kc;
            *(uint4*)(Bhi + (T * 64 + l) * 8) = pack8(vh);
            *(uint4*)(Blo + (T * 64 + l) * 8) = pack8(vl);
        }
    __builtin_amdgcn_wave_barrier();
    asm volatile("s_waitcnt lgkmcnt(0)" ::: "memory");
    __builtin_amdgcn_sched_barrier(0);
    const f32x4 z4 = {0.f, 0.f, 0.f, 0.f};
    // step1: Q[oy][x] = sum_y M0[oy][y] P[y][x]; all 16 tiles held in registers
    f32x4 accQ[4][4];
#pragma unroll
    for (int oyt = 0; oyt < 4; ++oyt) {
        bf16x8 Ah[2], Al[2];
#pragma unroll
        for (int kc = 0; kc < 2; ++kc) {
            Ah[kc] = *(const bf16x8*)(MA + (((size_t)(0 * 6 + e) * 4 + oyt) * 2 + kc) * 512 + l * 8);
            Al[kc] = *(const bf16x8*)(MA + (((size_t)(1 * 6 + e) * 4 + oyt) * 2 + kc) * 512 + l * 8);
        }
#pragma unroll
        for (int xt = 0; xt < 4; ++xt) {
            f32x4 acc = z4;
#pragma unroll
            for (int kc = 0; kc < 2; ++kc) {
                bf16x8 bh = *(const bf16x8*)(Bhi + ((xt * 2 + kc) * 64 + l) * 8);
                bf16x8 bl = *(const bf16x8*)(Blo + ((xt * 2 + kc) * 64 + l) * 8);
                acc = __builtin_amdgcn_mfma_f32_16x16x32_bf16(Ah[kc], bh, acc, 0, 0, 0);
                acc = __builtin_amdgcn_mfma_f32_16x16x32_bf16(Ah[kc], bl, acc, 0, 0, 0);
                acc = __builtin_amdgcn_mfma_f32_16x16x32_bf16(Al[kc], bh, acc, 0, 0, 0);
            }
            accQ[oyt][xt] = acc;
        }
    }
    // overwrite B buffers with Q (A-side fragment layout)
    __builtin_amdgcn_wave_barrier();
    asm volatile("s_waitcnt lgkmcnt(0)" ::: "memory");
    __builtin_amdgcn_sched_barrier(0);
#pragma unroll
    for (int oyt = 0; oyt < 4; ++oyt)
#pragma unroll
        for (int xt = 0; xt < 4; ++xt)
#pragma unroll
            for (int i = 0; i < 4; ++i) {
                int oy = oyt * 16 + lg * 4 + i;
                int xx = xt * 16 + lm;
                float qv = accQ[oyt][xt][i];
                unsigned short h = f2bf(qv);
                int off = offA(oy, xx);
                Bhi[off] = h; Blo[off] = f2bf(qv - bf2f(h));
            }
    __builtin_amdgcn_wave_barrier();
    asm volatile("s_waitcnt lgkmcnt(0)" ::: "memory");
    __builtin_amdgcn_sched_barrier(0);
    // step2: R[oy][ox] = sum_x Q[oy][x] M1[ox][x] (scaled), + max, in-place store
    float mmax = 0.f;
#pragma unroll 1
    for (int oyt = 0; oyt < 4; ++oyt) {
        bf16x8 Qh[2], Ql[2];
#pragma unroll
        for (int kc = 0; kc < 2; ++kc) {
            Qh[kc] = *(const bf16x8*)(Bhi + ((oyt * 2 + kc) * 64 + l) * 8);
            Ql[kc] = *(const bf16x8*)(Blo + ((oyt * 2 + kc) * 64 + l) * 8);
        }
#pragma unroll
        for (int oxt = 0; oxt < 4; ++oxt) {
            f32x4 acc = z4;
#pragma unroll
            for (int kc = 0; kc < 2; ++kc) {
                bf16x8 mh = *(const bf16x8*)(MB + (((size_t)(0 * 6 + e) * 4 + oxt) * 2 + kc) * 512 + l * 8);
                bf16x8 ml = *(const bf16x8*)(MB + (((size_t)(1 * 6 + e) * 4 + oxt) * 2 + kc) * 512 + l * 8);
                acc = __builtin_amdgcn_mfma_f32_16x16x32_bf16(Qh[kc], mh, acc, 0, 0, 0);
                acc = __builtin_amdgcn_mfma_f32_16x16x32_bf16(Qh[kc], ml, acc, 0, 0, 0);
                acc = __builtin_amdgcn_mfma_f32_16x16x32_bf16(Ql[kc], mh, acc, 0, 0, 0);
            }
            int ox = oxt * 16 + lm;
            if (ox < 50) {
#pragma unroll
                for (int i = 0; i < 4; ++i) {
                    int oy = oyt * 16 + lg * 4 + i;
                    if (oy < 50) {
                        float r = acc[i];
                        pb[oy * 50 + ox] = r;
                        mmax = fmaxf(mmax, r);
                    }
                }
            }
        }
    }
    for (int o = 32; o; o >>= 1) mmax = fmaxf(mmax, __shfl_xor(mmax, o));
    if (l == 0) atomicMax((int*)maxval, __float_as_int(mmax));
}

// ---------------- T1: blurred fp32 [b*6+e][z][y][x] -> X1 bf16 8-pack [b][z][y][x][8] ----------------
__global__ __launch_bounds__(256)
void t1_kernel(const float* __restrict__ A, unsigned short* __restrict__ X1) {
    const int z = blockIdx.x % 50, b = blockIdx.x / 50;
    const float* ab = A + (size_t)b * 6 * 125000 + (size_t)z * 2500;
    unsigned short* xb = X1 + ((size_t)b * 125000 + (size_t)z * 2500) * 8;
    for (int i = threadIdx.x; i < 2500; i += 256) {
        unsigned short v[6];
#pragma unroll
        for (int e = 0; e < 6; ++e) v[e] = f2bf(ab[(size_t)e * 125000 + i]);
        uint4 q;
        q.x = v[0] | ((unsigned)v[1] << 16);
        q.y = v[2] | ((unsigned)v[3] << 16);
        q.z = v[4] | ((unsigned)v[5] << 16);
        q.w = 0u;
        *(uint4*)(xb + (size_t)i * 8) = q;
    }
}

// ---------------- weight prep: generic B-fragment pack [cog][tap][ch][lane][8] ----------------
__global__ void wprep_kernel(const float* __restrict__ W, unsigned short* __restrict__ out,
                             int CIN, int NCH, int NCOG) {
    int idx = blockIdx.x * 256 + threadIdx.x;
    int total = NCOG * 27 * NCH * 64;
    if (idx >= total) return;
    int l = idx & 63;
    int r = idx >> 6;
    int ch = r % NCH; r /= NCH;
    int tap = r % 27;
    int cog = r / 27;
    int co = cog * 16 + (l & 15);
    unsigned short v[8];
#pragma unroll
    for (int j = 0; j < 8; ++j) {
        int ci = ch * 32 + (l >> 4) * 8 + j;
        v[j] = (ci < CIN) ? f2bf(W[((size_t)co * CIN + ci) * 27 + tap]) : (unsigned short)0;
    }
    uint4 q;
    q.x = v[0] | ((unsigned)v[1] << 16);
    q.y = v[2] | ((unsigned)v[3] << 16);
    q.z = v[4] | ((unsigned)v[5] << 16);
    q.w = v[6] | ((unsigned)v[7] << 16);
    ((uint4*)out)[idx] = q;
}

// ---------------- conv1 weight prep: 4-xsel packing [cog][9][lane][8] ----------------
__global__ void wprep1_kernel(const float* __restrict__ W, unsigned short* __restrict__ out) {
    int idx = blockIdx.x * 64 + threadIdx.x;
    if (idx >= 2 * 9 * 64) return;
    int l = idx & 63;
    int r = idx >> 6;
    int tg = r % 9;           // kz*3+ky
    int cog = r / 9;
    int xsel = l >> 4;
    int co = cog * 16 + (l & 15);
    unsigned short v[8];
#pragma unroll
    for (int j = 0; j < 8; ++j) {
        float wv = 0.f;
        if (j < 6 && xsel < 3) wv = W[((size_t)co * 6 + j) * 27 + tg * 3 + xsel];
        v[j] = f2bf(wv);
    }
    uint4 q;
    q.x = v[0] | ((unsigned)v[1] << 16);
    q.y = v[2] | ((unsigned)v[3] << 16);
    q.z = v[4] | ((unsigned)v[5] << 16);
    q.w = v[6] | ((unsigned)v[7] << 16);
    ((uint4*)out)[idx] = q;
}

// ---------------- conv1 MFMA: X1[50^3][8] -> X2[24^3][32], /max + bias + pool + relu ----------------
__global__ __launch_bounds__(64, 3)
void conv1_mfma(const unsigned short* __restrict__ X8, const unsigned short* __restrict__ wp1,
                const float* __restrict__ bias, const float* __restrict__ maxval,
                unsigned short* __restrict__ X2) {
    const int l = threadIdx.x, lm = l & 15, lg = l >> 4;
    const int q = (int)(gridDim.x >> 3);
    const int bid = ((int)blockIdx.x & 7) * q + ((int)blockIdx.x >> 3);
    const int s0 = bid * 8;
    const int r0 = s0 / 72;                 // uniform in block (8 | 72)
    const int cog = r0 % 2;
    const int pz  = (r0 / 2) % 24;
    const int b   = r0 / 48;
    uint4 B9[9];
    const uint4* wpb = (const uint4*)wp1 + cog * 9 * 64;
#pragma unroll
    for (int t = 0; t < 9; ++t) B9[t] = wpb[t * 64 + l];
    const float rmv = 1.0f / (*maxval);
    const float bia = bias[cog * 16 + lm];
    const unsigned short* Xb = X8 + (size_t)b * 125000 * 8;
    const f32x4 z4 = {0.f, 0.f, 0.f, 0.f};
#pragma unroll 1
    for (int si = 0; si < 8; ++si) {
        const int sid = s0 + si;
        const int xs = sid % 3;
        const int py = (sid / 3) % 24;
        const int x0 = xs * 16;
        f32x4 acc[2][2];
#pragma unroll
        for (int cz = 0; cz < 2; ++cz)
#pragma unroll
            for (int cy = 0; cy < 2; ++cy) acc[cz][cy] = z4;
#pragma unroll
        for (int zi = 0; zi < 4; ++zi) {
            const int zin = 2 * pz + zi;
#pragma unroll
            for (int yi = 0; yi < 4; ++yi) {
                const int yin = 2 * py + yi;
                const unsigned short* rowb = Xb + (size_t)(zin * 50 + yin) * 50 * 8;
                bf16x8 a = *(const bf16x8*)(rowb + (x0 + lm + lg) * 8);
#pragma unroll
                for (int cz = 0; cz < 2; ++cz) {
                    const int kz = zi - cz;
                    if (kz < 0 || kz > 2) continue;
#pragma unroll
                    for (int cy = 0; cy < 2; ++cy) {
                        const int ky = yi - cy;
                        if (ky < 0 || ky > 2) continue;
                        acc[cz][cy] = __builtin_amdgcn_mfma_f32_16x16x32_bf16(
                            a, *(const bf16x8*)&B9[kz * 3 + ky], acc[cz][cy], 0, 0, 0);
                    }
                }
            }
        }
        const int co = cog * 16 + lm;
#pragma unroll
        for (int ip = 0; ip < 2; ++ip) {
            float m0 = fmaxf(fmaxf(acc[0][0][2 * ip], acc[0][1][2 * ip]),
                             fmaxf(acc[1][0][2 * ip], acc[1][1][2 * ip]));
            float m1 = fmaxf(fmaxf(acc[0][0][2 * ip + 1], acc[0][1][2 * ip + 1]),
                             fmaxf(acc[1][0][2 * ip + 1], acc[1][1][2 * ip + 1]));
            float o = fmaxf(fmaxf(m0, m1) * rmv + bia, 0.f);
            int px = x0 / 2 + lg * 2 + ip;
            X2[((((size_t)b * 24 + pz) * 24 + py) * 24 + px) * 32 + co] = f2bf(o);
        }
    }
}

// ---------------- generic MFMA conv (conv2/conv3): bias + pool + relu -> bf16 ch-last ----------------
template <int DIN, int DP, int CI, int NCH, int NCOG, int NPY, int NXS, int SPB, int NPZ>
__global__ __launch_bounds__(64, 3)
void convN_mfma(const unsigned short* __restrict__ X, const unsigned short* __restrict__ wp,
                const float* __restrict__ bias, unsigned short* __restrict__ Y, int COUT) {
    const int l = threadIdx.x, lm = l & 15, lg = l >> 4;
    const int qq = (int)(gridDim.x >> 3);
    const int bid = ((int)blockIdx.x & 7) * qq + ((int)blockIdx.x >> 3);
    const int s0 = bid * SPB;
    const int r0 = s0 / (NPY * NXS);        // uniform in block
    const int cog = r0 % NCOG;
    const int pz  = (r0 / NCOG) % NPZ;
    const int b   = r0 / (NCOG * NPZ);
    const float bia = bias[cog * 16 + lm];
    const unsigned short* Xb = X + (size_t)b * DIN * DIN * DIN * CI;
    const uint4* wp4 = (const uint4*)wp;
    const f32x4 z4 = {0.f, 0.f, 0.f, 0.f};
#pragma unroll 1
    for (int si = 0; si < SPB; ++si) {
        const int sid = s0 + si;
        const int xs = sid % NXS;
        const int py = (sid / NXS) % NPY;
        const int x0 = xs * 16;
        int xo[3];
#pragma unroll
        for (int kx = 0; kx < 3; ++kx) {
            int xin = x0 + kx + lm;
            if (xin > DIN - 1) xin = DIN - 1;     // garbage rows masked at store
            xo[kx] = xin * CI + lg * 8;
        }
        f32x4 acc[2][2];
#pragma unroll
        for (int cz = 0; cz < 2; ++cz)
#pragma unroll
            for (int cy = 0; cy < 2; ++cy) acc[cz][cy] = z4;
#pragma unroll 1
        for (int ch = 0; ch < NCH; ++ch) {
            uint4 B[27];
            const uint4* wpb = wp4 + ((size_t)cog * 27 * NCH + ch) * 64;
#pragma unroll
            for (int t = 0; t < 27; ++t) B[t] = wpb[(size_t)t * NCH * 64 + l];
            const unsigned short* Xc = Xb + ch * 32;
#pragma unroll
            for (int zi = 0; zi < 4; ++zi) {
                const int zin = 2 * pz + zi;
#pragma unroll
                for (int yi = 0; yi < 4; ++yi) {
                    const int yin = 2 * py + yi;
                    const unsigned short* rowb = Xc + (size_t)(zin * DIN + yin) * DIN * CI;
#pragma unroll
                    for (int kx = 0; kx < 3; ++kx) {
                        bf16x8 a = *(const bf16x8*)(rowb + xo[kx]);
#pragma unroll
                        for (int cz = 0; cz < 2; ++cz) {
                            const int kz = zi - cz;
                            if (kz < 0 || kz > 2) continue;
#pragma unroll
                            for (int cy = 0; cy < 2; ++cy) {
                                const int ky = yi - cy;
                                if (ky < 0 || ky > 2) continue;
                                const int tap = (kz * 3 + ky) * 3 + kx;
                                acc[cz][cy] = __builtin_amdgcn_mfma_f32_16x16x32_bf16(
                                    a, *(const bf16x8*)&B[tap], acc[cz][cy], 0, 0, 0);
                            }
                        }
                    }
                }
            }
        }
        const int co = cog * 16 + lm;
#pragma unroll
        for (int ip = 0; ip < 2; ++ip) {
            float m0 = fmaxf(fmaxf(acc[0][0][2 * ip], acc[0][1][2 * ip]),
                             fmaxf(acc[1][0][2 * ip], acc[1][1][2 * ip]));
            float m1 = fmaxf(fmaxf(acc[0][0][2 * ip + 1], acc[0][1][2 * ip + 1]),
                             fmaxf(acc[1][0][2 * ip + 1], acc[1][1][2 * ip + 1]));
            float o = fmaxf(fmaxf(m0, m1) + bia, 0.f);
            int px = x0 / 2 + lg * 2 + ip;
            if (px < DP)
                Y[((((size_t)b * DP + pz) * DP + py) * DP + px) * COUT + co] = f2bf(o);
        }
    }
}

// ---------------- conv4: channels-last bf16 in, fp32 weights; wave per (b,co) ----------------
__global__ void conv4_kernel(const unsigned short* __restrict__ X4, const float* __restrict__ w,
                             const float* __restrict__ bias, float* __restrict__ out) {
    int wid = (int)((blockIdx.x * blockDim.x + threadIdx.x) >> 6);
    int lane = threadIdx.x & 63;
    if (wid >= NB * 256) return;
    int b = wid >> 8, co = wid & 255;
    float acc[8];
#pragma unroll
    for (int i = 0; i < 8; ++i) acc[i] = 0.f;
    for (int half = 0; half < 2; ++half) {
        int ci = lane + half * 64;
        float win[64];
#pragma unroll
        for (int v = 0; v < 64; ++v)
            win[v] = bf2f(X4[((size_t)b * 64 + v) * 128 + ci]);
        const float* wc = w + ((size_t)co * 128 + ci) * 27;
        float wr[27];
#pragma unroll
        for (int i = 0; i < 27; ++i) wr[i] = wc[i];
#pragma unroll
        for (int kz = 0; kz < 3; ++kz)
#pragma unroll
            for (int ky = 0; ky < 3; ++ky)
#pragma unroll
                for (int kx = 0; kx < 3; ++kx) {
                    float wv = wr[(kz * 3 + ky) * 3 + kx];
#pragma unroll
                    for (int oz = 0; oz < 2; ++oz)
#pragma unroll
                        for (int oy = 0; oy < 2; ++oy)
#pragma unroll
                            for (int ox = 0; ox < 2; ++ox)
                                acc[(oz * 2 + oy) * 2 + ox] =
                                    fmaf(wv, win[((oz + kz) * 4 + (oy + ky)) * 4 + ox + kx],
                                         acc[(oz * 2 + oy) * 2 + ox]);
                }
    }
#pragma unroll
    for (int o = 32; o; o >>= 1)
#pragma unroll
        for (int i = 0; i < 8; ++i) acc[i] += __shfl_xor(acc[i], o);
    if (lane == 0) {
        float m = acc[0];
#pragma unroll
        for (int i = 1; i < 8; ++i) m = fmaxf(m, acc[i]);
        out[(size_t)b * 256 + co] = fmaxf(m + bias[co], 0.f);
    }
}

// ---------------- FC head: (8,256) -> relu(128) -> 29 ----------------
__global__ void head_kernel(const float* __restrict__ v,
                            const float* __restrict__ fw1, const float* __restrict__ fb1,
                            const float* __restrict__ fw2, const float* __restrict__ fb2,
                            float* __restrict__ out) {
    int b = blockIdx.x, t = threadIdx.x;
    __shared__ float sv[256];
    __shared__ float s1[128];
    sv[t] = v[b * 256 + t];
    sv[t + 128] = v[b * 256 + t + 128];
    __syncthreads();
    float acc = fb1[t];
    const float* wr = fw1 + t * 256;
    for (int k = 0; k < 256; ++k) acc = fmaf(wr[k], sv[k], acc);
    s1[t] = fmaxf(acc, 0.f);
    __syncthreads();
    if (t < 29) {
        float a2 = fb2[t];
        const float* w2 = fw2 + t * 128;
        for (int k = 0; k < 128; ++k) a2 = fmaf(w2[k], s1[k], a2);
        out[b * 29 + t] = a2;
    }
}

extern "C" void kernel_launch(void* const* d_in, const int* in_sizes, int n_in,
                              void* d_out, int out_size, void* d_ws, size_t ws_size,
                              hipStream_t stream) {
    const float* x     = (const float*)d_in[0];
    const float* sigma = (const float*)d_in[1];
    const float* w1    = (const float*)d_in[2];
    const float* b1    = (const float*)d_in[3];
    const float* w2    = (const float*)d_in[4];
    const float* b2    = (const float*)d_in[5];
    const float* w3    = (const float*)d_in[6];
    const float* b3    = (const float*)d_in[7];
    const float* w4    = (const float*)d_in[8];
    const float* b4    = (const float*)d_in[9];
    const float* fw1   = (const float*)d_in[10];
    const float* fb1   = (const float*)d_in[11];
    const float* fw2   = (const float*)d_in[12];
    const float* fb2   = (const float*)d_in[13];
    float* out = (float*)d_out;

    // ---- workspace layout (~50 MB) ----
    float* W1 = (float*)d_ws;                                 // 6,000,000 f
    unsigned short* X1  = (unsigned short*)(W1 + NVOX);       // 8,000,064
    unsigned short* X2  = X1 + 8000064;                       // 3,538,944
    unsigned short* X3  = X2 + 3538944;                       // 681,472
    unsigned short* X4  = X3 + 681472;                        // 65,536
    unsigned short* wp1 = X4 + 65536;                         // 9,216
    unsigned short* wp2 = wp1 + 9216;                         // 55,296
    unsigned short* wp3 = wp2 + 55296;                        // 221,184
    unsigned short* MA  = wp3 + 221184;                       // 49,152
    unsigned short* MB  = MA + 49152;                         // 49,152
    float* mx = (float*)(MB + 49152);                         // 1
    float* v4 = mx + 1;                                       // 2,048 f

    taps_kernel<<<1, 512, 0, stream>>>(sigma, MA, MB, mx);

    // blur: K1 (z-axis) then fused K2 (y+x axes, scaled taps, global max), in-place
    blur_k1<<<NB * NE * 50, 64, 0, stream>>>(x, W1, MA);
    blur_k2<<<NB * NE * 50, 64, 0, stream>>>(W1, MA, MB, mx);

    // channels-last bf16 (8-pack) + weight fragment packing
    t1_kernel<<<400, 256, 0, stream>>>(W1, X1);
    wprep1_kernel<<<18, 64, 0, stream>>>(w1, wp1);
    wprep_kernel<<<27, 256, 0, stream>>>(w2, wp2, 32, 1, 4);
    wprep_kernel<<<108, 256, 0, stream>>>(w3, wp3, 64, 2, 8);

    // conv1: 4-xsel K-packing, XCD-swizzled
    conv1_mfma<<<3456, 64, 0, stream>>>(X1, wp1, b1, mx, X2);
    // conv2 / conv3 (XCD-swizzled inside)
    convN_mfma<24, 11, 32, 1, 4, 11, 2, 2, 11><<<3872, 64, 0, stream>>>(X2, wp2, b2, X3, 64);
    convN_mfma<11, 4, 64, 2, 8, 4, 1, 1, 4><<<1024, 64, 0, stream>>>(X3, wp3, b3, X4, 128);

    // conv4 (VALU, channels-last bf16 in) + head
    conv4_kernel<<<512, 256, 0, stream>>>(X4, w4, b4, v4);
    head_kernel<<<8, 128, 0, stream>>>(v4, fw1, fb1, fw2, fb2, out);
}

// Round 15
// 205.500 us; speedup vs baseline: 1.7023x; 1.0328x over previous
//
#include <hip/hip_runtime.h>
#include <math.h>

#define DIMX 50
#define KK   51
#define NE   6
#define NB   8
#define NVOX ((size_t)NB * NE * DIMX * DIMX * DIMX)  // 6,000,000

typedef short bf16x8 __attribute__((ext_vector_type(8)));
typedef float f32x4  __attribute__((ext_vector_type(4)));

__device__ __forceinline__ unsigned short f2bf(float f) {
    unsigned u = __float_as_uint(f);
    u += 0x7fffu + ((u >> 16) & 1u);      // RNE; inputs finite
    return (unsigned short)(u >> 16);
}
__device__ __forceinline__ float bf2f(unsigned short h) {
    return __uint_as_float((unsigned)h << 16);
}
__device__ __forceinline__ uint4 pack8(const unsigned short v[8]) {
    uint4 q;
    q.x = v[0] | ((unsigned)v[1] << 16);
    q.y = v[2] | ((unsigned)v[3] << 16);
    q.z = v[4] | ((unsigned)v[5] << 16);
    q.w = v[6] | ((unsigned)v[7] << 16);
    return q;
}
// A-side fragment-linear offset: own=o(row), k; frag=((o>>4)*2+(k>>5)), lane=((k>>3)&3)*16+(o&15)
__device__ __forceinline__ int offA(int o, int k) {
    return ((((o >> 4) * 2 + (k >> 5)) * 64 + ((k >> 3) & 3) * 16 + (o & 15)) << 3) + (k & 7);
}

// -------- taps + MFMA-fragment-packed blur matrices --------
// MA[hl][e][t][kc][l][j]: A-side frags of RAW taps (own=o, k=z), val=tap[z-o+25]
// MB[hl][e][t][kc][l][j]: B-side frags of SCALED taps (own=ox, k=x), val=stap[x-ox+25]
__global__ void taps_kernel(const float* __restrict__ sigma,
                            unsigned short* __restrict__ MA, unsigned short* __restrict__ MB,
                            float* __restrict__ maxval) {
    __shared__ float sg[NE * KK];
    __shared__ float sgs[NE * KK];
    __shared__ float ssum[NE];
    int t = threadIdx.x;
    if (t == 0) *maxval = 0.f;
    if (t < NE * KK) {
        int e = t / KK, i = t % KK;
        float d = (float)i - 25.0f;
        float var = sigma[e] * sigma[e];
        sg[t] = expf(-d * d / (2.f * var));
    }
    __syncthreads();
    if (t < NE) {
        float s = 0.f;
        for (int i = 0; i < KK; ++i) s += sg[t * KK + i];
        ssum[t] = s;
    }
    __syncthreads();
    if (t < NE * KK) {
        int e = t / KK;
        float S = 0.f;
        for (int e2 = 0; e2 < NE; ++e2) {
            float var2 = sigma[e2] * sigma[e2];
            float a2 = 1.f / (2.f * (float)M_PI * var2);
            float se = ssum[e2];
            S += a2 * se * se * se;
        }
        float var = sigma[e] * sigma[e];
        float a = 1.f / (2.f * (float)M_PI * var);
        sgs[t] = sg[t] * (a / S);
    }
    __syncthreads();
    const int TOT = 2 * 6 * 4 * 2 * 64 * 8;   // 49152 per matrix
    for (int i = t; i < 2 * TOT; i += 512) {
        int which = i / TOT;                   // 0=MA(raw) 1=MB(scaled)
        int r = i % TOT;
        int q = r;
        int j = q & 7; q >>= 3;
        int l = q & 63; q >>= 6;
        int kc = q & 1; q >>= 1;
        int tile = q & 3; q >>= 2;
        int e = q % 6; q /= 6;
        int hl = q;                            // 0=hi 1=lo
        int own = tile * 16 + (l & 15);
        int k   = kc * 32 + ((l >> 4) << 3) + j;
        float v = 0.f;
        if (own < 50 && k < 50) {
            int d = k - own + 25;
            if (d >= 0 && d < KK) v = (which == 0 ? sg : sgs)[e * KK + d];
        }
        unsigned short h = f2bf(v);
        unsigned short out = (hl == 0) ? h : f2bf(v - bf2f(h));
        (which == 0 ? MA : MB)[r] = out;
    }
}

// -------- K1: z-axis blur via MFMA; NO LDS (B fragments are lane-identity) --------
__global__ __launch_bounds__(64)
void blur_k1(const float* __restrict__ in, float* __restrict__ W1,
             const unsigned short* __restrict__ MA) {
    const int l = threadIdx.x, lm = l & 15, lg = l >> 4;
    const int y = blockIdx.x % 50, be = blockIdx.x / 50, e = be % 6;
    const float* pb = in + (size_t)be * 125000 + y * 50;
    bf16x8 Ah[4][2], Al[4][2];
#pragma unroll
    for (int ozt = 0; ozt < 4; ++ozt)
#pragma unroll
        for (int kc = 0; kc < 2; ++kc) {
            Ah[ozt][kc] = *(const bf16x8*)(MA + (((size_t)(0 * 6 + e) * 4 + ozt) * 2 + kc) * 512 + l * 8);
            Al[ozt][kc] = *(const bf16x8*)(MA + (((size_t)(1 * 6 + e) * 4 + ozt) * 2 + kc) * 512 + l * 8);
        }
    float* ob = W1 + (size_t)be * 125000 + y * 50;
    const f32x4 z4 = {0.f, 0.f, 0.f, 0.f};
#pragma unroll 1
    for (int xt = 0; xt < 4; ++xt) {
        const int xx = xt * 16 + lm;
        bf16x8 bh[2], bl[2];
#pragma unroll
        for (int kc = 0; kc < 2; ++kc) {
            unsigned short vh[8], vl[8];
#pragma unroll
            for (int j = 0; j < 8; ++j) {
                int z = kc * 32 + lg * 8 + j;
                float v = (z < 50 && xx < 50) ? pb[(size_t)z * 2500 + xx] : 0.f;
                unsigned short h = f2bf(v);
                vh[j] = h; vl[j] = f2bf(v - bf2f(h));
            }
            uint4 qh = pack8(vh), ql = pack8(vl);
            bh[kc] = *(bf16x8*)&qh; bl[kc] = *(bf16x8*)&ql;
        }
        f32x4 acc[4];
#pragma unroll
        for (int ozt = 0; ozt < 4; ++ozt) acc[ozt] = z4;
#pragma unroll
        for (int ozt = 0; ozt < 4; ++ozt)
#pragma unroll
            for (int kc = 0; kc < 2; ++kc) {
                acc[ozt] = __builtin_amdgcn_mfma_f32_16x16x32_bf16(Ah[ozt][kc], bh[kc], acc[ozt], 0, 0, 0);
                acc[ozt] = __builtin_amdgcn_mfma_f32_16x16x32_bf16(Ah[ozt][kc], bl[kc], acc[ozt], 0, 0, 0);
                acc[ozt] = __builtin_amdgcn_mfma_f32_16x16x32_bf16(Al[ozt][kc], bh[kc], acc[ozt], 0, 0, 0);
            }
        if (xx < 50) {
#pragma unroll
            for (int ozt = 0; ozt < 4; ++ozt)
#pragma unroll
                for (int i = 0; i < 4; ++i) {
                    int oz = ozt * 16 + lg * 4 + i;
                    if (oz < 50) ob[(size_t)oz * 2500 + xx] = acc[ozt][i];
                }
        }
    }
}

// -------- K2: fused y-blur + x-blur(scaled) + global max; writes X1 bf16 8-pack directly --------
// Grid logical order [(b,z)][e] with bijective XCD swizzle so all 6 e-blocks of a (b,z)
// share one XCD (L2 merges the 2B-interleaved X1 writes). LDS = Q exchange only (16 KB).
__global__ __launch_bounds__(64)
void blur_k2(const float* __restrict__ W1, const unsigned short* __restrict__ MA,
             const unsigned short* __restrict__ MB, unsigned short* __restrict__ X1,
             float* __restrict__ maxval) {
    __shared__ unsigned short Qhi[4096], Qlo[4096];
    const int l = threadIdx.x, lm = l & 15, lg = l >> 4;
    const int q8 = (int)(gridDim.x >> 3);
    const int logical = ((int)blockIdx.x & 7) * q8 + ((int)blockIdx.x >> 3);
    const int e = logical % 6, bz = logical / 6, z = bz % 50, b = bz / 50;
    const float* pb = W1 + (size_t)(b * 6 + e) * 125000 + (size_t)z * 2500;
    // B fragments (lane-identity, registers): plane P[y][x]
    bf16x8 Bh[4][2], Bl[4][2];
#pragma unroll
    for (int xt = 0; xt < 4; ++xt) {
        const int xx = xt * 16 + lm;
#pragma unroll
        for (int kc = 0; kc < 2; ++kc) {
            unsigned short vh[8], vl[8];
#pragma unroll
            for (int j = 0; j < 8; ++j) {
                int yy = kc * 32 + lg * 8 + j;
                float v = (yy < 50 && xx < 50) ? pb[yy * 50 + xx] : 0.f;
                unsigned short h = f2bf(v);
                vh[j] = h; vl[j] = f2bf(v - bf2f(h));
            }
            uint4 qh = pack8(vh), ql = pack8(vl);
            Bh[xt][kc] = *(bf16x8*)&qh; Bl[xt][kc] = *(bf16x8*)&ql;
        }
    }
    const f32x4 z4 = {0.f, 0.f, 0.f, 0.f};
    // step1: Q[oy][x] = sum_y M0[oy][y] P[y][x]; Q -> LDS in A-fragment layout
#pragma unroll 1
    for (int oyt = 0; oyt < 4; ++oyt) {
        bf16x8 Ah[2], Al[2];
#pragma unroll
        for (int kc = 0; kc < 2; ++kc) {
            Ah[kc] = *(const bf16x8*)(MA + (((size_t)(0 * 6 + e) * 4 + oyt) * 2 + kc) * 512 + l * 8);
            Al[kc] = *(const bf16x8*)(MA + (((size_t)(1 * 6 + e) * 4 + oyt) * 2 + kc) * 512 + l * 8);
        }
#pragma unroll
        for (int xt = 0; xt < 4; ++xt) {
            f32x4 acc = z4;
#pragma unroll
            for (int kc = 0; kc < 2; ++kc) {
                acc = __builtin_amdgcn_mfma_f32_16x16x32_bf16(Ah[kc], Bh[xt][kc], acc, 0, 0, 0);
                acc = __builtin_amdgcn_mfma_f32_16x16x32_bf16(Ah[kc], Bl[xt][kc], acc, 0, 0, 0);
                acc = __builtin_amdgcn_mfma_f32_16x16x32_bf16(Al[kc], Bh[xt][kc], acc, 0, 0, 0);
            }
#pragma unroll
            for (int i = 0; i < 4; ++i) {
                int oy = oyt * 16 + lg * 4 + i;
                int xx = xt * 16 + lm;
                float qv = acc[i];
                unsigned short h = f2bf(qv);
                int off = offA(oy, xx);
                Qhi[off] = h; Qlo[off] = f2bf(qv - bf2f(h));
            }
        }
    }
    __builtin_amdgcn_wave_barrier();
    asm volatile("s_waitcnt lgkmcnt(0)" ::: "memory");
    __builtin_amdgcn_sched_barrier(0);
    // step2: R[oy][ox] = sum_x Q[oy][x] M1[ox][x] (scaled) -> X1 bf16, + global max
    float mmax = 0.f;
    unsigned short* xb = X1 + ((size_t)b * 125000 + (size_t)z * 2500) * 8 + e;
#pragma unroll 1
    for (int oyt = 0; oyt < 4; ++oyt) {
        bf16x8 Qh[2], Ql[2];
#pragma unroll
        for (int kc = 0; kc < 2; ++kc) {
            Qh[kc] = *(const bf16x8*)(Qhi + ((oyt * 2 + kc) * 64 + l) * 8);
            Ql[kc] = *(const bf16x8*)(Qlo + ((oyt * 2 + kc) * 64 + l) * 8);
        }
#pragma unroll
        for (int oxt = 0; oxt < 4; ++oxt) {
            f32x4 acc = z4;
#pragma unroll
            for (int kc = 0; kc < 2; ++kc) {
                bf16x8 mh = *(const bf16x8*)(MB + (((size_t)(0 * 6 + e) * 4 + oxt) * 2 + kc) * 512 + l * 8);
                bf16x8 ml = *(const bf16x8*)(MB + (((size_t)(1 * 6 + e) * 4 + oxt) * 2 + kc) * 512 + l * 8);
                acc = __builtin_amdgcn_mfma_f32_16x16x32_bf16(Qh[kc], mh, acc, 0, 0, 0);
                acc = __builtin_amdgcn_mfma_f32_16x16x32_bf16(Qh[kc], ml, acc, 0, 0, 0);
                acc = __builtin_amdgcn_mfma_f32_16x16x32_bf16(Ql[kc], mh, acc, 0, 0, 0);
            }
            int ox = oxt * 16 + lm;
            if (ox < 50) {
#pragma unroll
                for (int i = 0; i < 4; ++i) {
                    int oy = oyt * 16 + lg * 4 + i;
                    if (oy < 50) {
                        float r = acc[i];
                        xb[((size_t)oy * 50 + ox) * 8] = f2bf(r);
                        mmax = fmaxf(mmax, r);
                    }
                }
            }
        }
    }
    for (int o = 32; o; o >>= 1) mmax = fmaxf(mmax, __shfl_xor(mmax, o));
    if (l == 0) atomicMax((int*)maxval, __float_as_int(mmax));
}

// ---------------- weight prep: generic B-fragment pack [cog][tap][ch][lane][8] ----------------
__global__ void wprep_kernel(const float* __restrict__ W, unsigned short* __restrict__ out,
                             int CIN, int NCH, int NCOG) {
    int idx = blockIdx.x * 256 + threadIdx.x;
    int total = NCOG * 27 * NCH * 64;
    if (idx >= total) return;
    int l = idx & 63;
    int r = idx >> 6;
    int ch = r % NCH; r /= NCH;
    int tap = r % 27;
    int cog = r / 27;
    int co = cog * 16 + (l & 15);
    unsigned short v[8];
#pragma unroll
    for (int j = 0; j < 8; ++j) {
        int ci = ch * 32 + (l >> 4) * 8 + j;
        v[j] = (ci < CIN) ? f2bf(W[((size_t)co * CIN + ci) * 27 + tap]) : (unsigned short)0;
    }
    ((uint4*)out)[idx] = pack8(v);
}

// ---------------- conv1 weight prep: 4-xsel packing [cog][9][lane][8] ----------------
__global__ void wprep1_kernel(const float* __restrict__ W, unsigned short* __restrict__ out) {
    int idx = blockIdx.x * 64 + threadIdx.x;
    if (idx >= 2 * 9 * 64) return;
    int l = idx & 63;
    int r = idx >> 6;
    int tg = r % 9;           // kz*3+ky
    int cog = r / 9;
    int xsel = l >> 4;
    int co = cog * 16 + (l & 15);
    unsigned short v[8];
#pragma unroll
    for (int j = 0; j < 8; ++j) {
        float wv = 0.f;
        if (j < 6 && xsel < 3) wv = W[((size_t)co * 6 + j) * 27 + tg * 3 + xsel];
        v[j] = f2bf(wv);
    }
    ((uint4*)out)[idx] = pack8(v);
}

// ---------------- conv1 MFMA: X1[50^3][8] -> X2[24^3][32], /max + bias + pool + relu ----------------
__global__ __launch_bounds__(64, 3)
void conv1_mfma(const unsigned short* __restrict__ X8, const unsigned short* __restrict__ wp1,
                const float* __restrict__ bias, const float* __restrict__ maxval,
                unsigned short* __restrict__ X2) {
    const int l = threadIdx.x, lm = l & 15, lg = l >> 4;
    const int q = (int)(gridDim.x >> 3);
    const int bid = ((int)blockIdx.x & 7) * q + ((int)blockIdx.x >> 3);
    const int s0 = bid * 8;
    const int r0 = s0 / 72;                 // uniform in block (8 | 72)
    const int cog = r0 % 2;
    const int pz  = (r0 / 2) % 24;
    const int b   = r0 / 48;
    uint4 B9[9];
    const uint4* wpb = (const uint4*)wp1 + cog * 9 * 64;
#pragma unroll
    for (int t = 0; t < 9; ++t) B9[t] = wpb[t * 64 + l];
    const float rmv = 1.0f / (*maxval);
    const float bia = bias[cog * 16 + lm];
    const unsigned short* Xb = X8 + (size_t)b * 125000 * 8;
    const f32x4 z4 = {0.f, 0.f, 0.f, 0.f};
#pragma unroll 1
    for (int si = 0; si < 8; ++si) {
        const int sid = s0 + si;
        const int xs = sid % 3;
        const int py = (sid / 3) % 24;
        const int x0 = xs * 16;
        f32x4 acc[2][2];
#pragma unroll
        for (int cz = 0; cz < 2; ++cz)
#pragma unroll
            for (int cy = 0; cy < 2; ++cy) acc[cz][cy] = z4;
#pragma unroll
        for (int zi = 0; zi < 4; ++zi) {
            const int zin = 2 * pz + zi;
#pragma unroll
            for (int yi = 0; yi < 4; ++yi) {
                const int yin = 2 * py + yi;
                const unsigned short* rowb = Xb + (size_t)(zin * 50 + yin) * 50 * 8;
                bf16x8 a = *(const bf16x8*)(rowb + (x0 + lm + lg) * 8);
#pragma unroll
                for (int cz = 0; cz < 2; ++cz) {
                    const int kz = zi - cz;
                    if (kz < 0 || kz > 2) continue;
#pragma unroll
                    for (int cy = 0; cy < 2; ++cy) {
                        const int ky = yi - cy;
                        if (ky < 0 || ky > 2) continue;
                        acc[cz][cy] = __builtin_amdgcn_mfma_f32_16x16x32_bf16(
                            a, *(const bf16x8*)&B9[kz * 3 + ky], acc[cz][cy], 0, 0, 0);
                    }
                }
            }
        }
        const int co = cog * 16 + lm;
#pragma unroll
        for (int ip = 0; ip < 2; ++ip) {
            float m0 = fmaxf(fmaxf(acc[0][0][2 * ip], acc[0][1][2 * ip]),
                             fmaxf(acc[1][0][2 * ip], acc[1][1][2 * ip]));
            float m1 = fmaxf(fmaxf(acc[0][0][2 * ip + 1], acc[0][1][2 * ip + 1]),
                             fmaxf(acc[1][0][2 * ip + 1], acc[1][1][2 * ip + 1]));
            float o = fmaxf(fmaxf(m0, m1) * rmv + bia, 0.f);
            int px = x0 / 2 + lg * 2 + ip;
            X2[((((size_t)b * 24 + pz) * 24 + py) * 24 + px) * 32 + co] = f2bf(o);
        }
    }
}

// ---------------- generic MFMA conv (conv2/conv3): bias + pool + relu -> bf16 ch-last ----------------
template <int DIN, int DP, int CI, int NCH, int NCOG, int NPY, int NXS, int SPB, int NPZ>
__global__ __launch_bounds__(64, 3)
void convN_mfma(const unsigned short* __restrict__ X, const unsigned short* __restrict__ wp,
                const float* __restrict__ bias, unsigned short* __restrict__ Y, int COUT) {
    const int l = threadIdx.x, lm = l & 15, lg = l >> 4;
    const int qq = (int)(gridDim.x >> 3);
    const int bid = ((int)blockIdx.x & 7) * qq + ((int)blockIdx.x >> 3);
    const int s0 = bid * SPB;
    const int r0 = s0 / (NPY * NXS);        // uniform in block
    const int cog = r0 % NCOG;
    const int pz  = (r0 / NCOG) % NPZ;
    const int b   = r0 / (NCOG * NPZ);
    const float bia = bias[cog * 16 + lm];
    const unsigned short* Xb = X + (size_t)b * DIN * DIN * DIN * CI;
    const uint4* wp4 = (const uint4*)wp;
    const f32x4 z4 = {0.f, 0.f, 0.f, 0.f};
#pragma unroll 1
    for (int si = 0; si < SPB; ++si) {
        const int sid = s0 + si;
        const int xs = sid % NXS;
        const int py = (sid / NXS) % NPY;
        const int x0 = xs * 16;
        int xo[3];
#pragma unroll
        for (int kx = 0; kx < 3; ++kx) {
            int xin = x0 + kx + lm;
            if (xin > DIN - 1) xin = DIN - 1;     // garbage rows masked at store
            xo[kx] = xin * CI + lg * 8;
        }
        f32x4 acc[2][2];
#pragma unroll
        for (int cz = 0; cz < 2; ++cz)
#pragma unroll
            for (int cy = 0; cy < 2; ++cy) acc[cz][cy] = z4;
#pragma unroll 1
        for (int ch = 0; ch < NCH; ++ch) {
            uint4 B[27];
            const uint4* wpb = wp4 + ((size_t)cog * 27 * NCH + ch) * 64;
#pragma unroll
            for (int t = 0; t < 27; ++t) B[t] = wpb[(size_t)t * NCH * 64 + l];
            const unsigned short* Xc = Xb + ch * 32;
#pragma unroll
            for (int zi = 0; zi < 4; ++zi) {
                const int zin = 2 * pz + zi;
#pragma unroll
                for (int yi = 0; yi < 4; ++yi) {
                    const int yin = 2 * py + yi;
                    const unsigned short* rowb = Xc + (size_t)(zin * DIN + yin) * DIN * CI;
#pragma unroll
                    for (int kx = 0; kx < 3; ++kx) {
                        bf16x8 a = *(const bf16x8*)(rowb + xo[kx]);
#pragma unroll
                        for (int cz = 0; cz < 2; ++cz) {
                            const int kz = zi - cz;
                            if (kz < 0 || kz > 2) continue;
#pragma unroll
                            for (int cy = 0; cy < 2; ++cy) {
                                const int ky = yi - cy;
                                if (ky < 0 || ky > 2) continue;
                                const int tap = (kz * 3 + ky) * 3 + kx;
                                acc[cz][cy] = __builtin_amdgcn_mfma_f32_16x16x32_bf16(
                                    a, *(const bf16x8*)&B[tap], acc[cz][cy], 0, 0, 0);
                            }
                        }
                    }
                }
            }
        }
        const int co = cog * 16 + lm;
#pragma unroll
        for (int ip = 0; ip < 2; ++ip) {
            float m0 = fmaxf(fmaxf(acc[0][0][2 * ip], acc[0][1][2 * ip]),
                             fmaxf(acc[1][0][2 * ip], acc[1][1][2 * ip]));
            float m1 = fmaxf(fmaxf(acc[0][0][2 * ip + 1], acc[0][1][2 * ip + 1]),
                             fmaxf(acc[1][0][2 * ip + 1], acc[1][1][2 * ip + 1]));
            float o = fmaxf(fmaxf(m0, m1) + bia, 0.f);
            int px = x0 / 2 + lg * 2 + ip;
            if (px < DP)
                Y[((((size_t)b * DP + pz) * DP + py) * DP + px) * COUT + co] = f2bf(o);
        }
    }
}

// ---------------- conv4: channels-last bf16 in, fp32 weights; wave per (b,co) ----------------
__global__ void conv4_kernel(const unsigned short* __restrict__ X4, const float* __restrict__ w,
                             const float* __restrict__ bias, float* __restrict__ out) {
    int wid = (int)((blockIdx.x * blockDim.x + threadIdx.x) >> 6);
    int lane = threadIdx.x & 63;
    if (wid >= NB * 256) return;
    int b = wid >> 8, co = wid & 255;
    float acc[8];
#pragma unroll
    for (int i = 0; i < 8; ++i) acc[i] = 0.f;
    for (int half = 0; half < 2; ++half) {
        int ci = lane + half * 64;
        float win[64];
#pragma unroll
        for (int v = 0; v < 64; ++v)
            win[v] = bf2f(X4[((size_t)b * 64 + v) * 128 + ci]);
        const float* wc = w + ((size_t)co * 128 + ci) * 27;
        float wr[27];
#pragma unroll
        for (int i = 0; i < 27; ++i) wr[i] = wc[i];
#pragma unroll
        for (int kz = 0; kz < 3; ++kz)
#pragma unroll
            for (int ky = 0; ky < 3; ++ky)
#pragma unroll
                for (int kx = 0; kx < 3; ++kx) {
                    float wv = wr[(kz * 3 + ky) * 3 + kx];
#pragma unroll
                    for (int oz = 0; oz < 2; ++oz)
#pragma unroll
                        for (int oy = 0; oy < 2; ++oy)
#pragma unroll
                            for (int ox = 0; ox < 2; ++ox)
                                acc[(oz * 2 + oy) * 2 + ox] =
                                    fmaf(wv, win[((oz + kz) * 4 + (oy + ky)) * 4 + ox + kx],
                                         acc[(oz * 2 + oy) * 2 + ox]);
                }
    }
#pragma unroll
    for (int o = 32; o; o >>= 1)
#pragma unroll
        for (int i = 0; i < 8; ++i) acc[i] += __shfl_xor(acc[i], o);
    if (lane == 0) {
        float m = acc[0];
#pragma unroll
        for (int i = 1; i < 8; ++i) m = fmaxf(m, acc[i]);
        out[(size_t)b * 256 + co] = fmaxf(m + bias[co], 0.f);
    }
}

// ---------------- FC head: (8,256) -> relu(128) -> 29 ----------------
__global__ void head_kernel(const float* __restrict__ v,
                            const float* __restrict__ fw1, const float* __restrict__ fb1,
                            const float* __restrict__ fw2, const float* __restrict__ fb2,
                            float* __restrict__ out) {
    int b = blockIdx.x, t = threadIdx.x;
    __shared__ float sv[256];
    __shared__ float s1[128];
    sv[t] = v[b * 256 + t];
    sv[t + 128] = v[b * 256 + t + 128];
    __syncthreads();
    float acc = fb1[t];
    const float* wr = fw1 + t * 256;
    for (int k = 0; k < 256; ++k) acc = fmaf(wr[k], sv[k], acc);
    s1[t] = fmaxf(acc, 0.f);
    __syncthreads();
    if (t < 29) {
        float a2 = fb2[t];
        const float* w2 = fw2 + t * 128;
        for (int k = 0; k < 128; ++k) a2 = fmaf(w2[k], s1[k], a2);
        out[b * 29 + t] = a2;
    }
}

extern "C" void kernel_launch(void* const* d_in, const int* in_sizes, int n_in,
                              void* d_out, int out_size, void* d_ws, size_t ws_size,
                              hipStream_t stream) {
    const float* x     = (const float*)d_in[0];
    const float* sigma = (const float*)d_in[1];
    const float* w1    = (const float*)d_in[2];
    const float* b1    = (const float*)d_in[3];
    const float* w2    = (const float*)d_in[4];
    const float* b2    = (const float*)d_in[5];
    const float* w3    = (const float*)d_in[6];
    const float* b3    = (const float*)d_in[7];
    const float* w4    = (const float*)d_in[8];
    const float* b4    = (const float*)d_in[9];
    const float* fw1   = (const float*)d_in[10];
    const float* fb1   = (const float*)d_in[11];
    const float* fw2   = (const float*)d_in[12];
    const float* fb2   = (const float*)d_in[13];
    float* out = (float*)d_out;

    // ---- workspace layout (~50 MB) ----
    float* W1 = (float*)d_ws;                                 // 6,000,000 f
    unsigned short* X1  = (unsigned short*)(W1 + NVOX);       // 8,000,064
    unsigned short* X2  = X1 + 8000064;                       // 3,538,944
    unsigned short* X3  = X2 + 3538944;                       // 681,472
    unsigned short* X4  = X3 + 681472;                        // 65,536
    unsigned short* wp1 = X4 + 65536;                         // 9,216
    unsigned short* wp2 = wp1 + 9216;                         // 55,296
    unsigned short* wp3 = wp2 + 55296;                        // 221,184
    unsigned short* MA  = wp3 + 221184;                       // 49,152
    unsigned short* MB  = MA + 49152;                         // 49,152
    float* mx = (float*)(MB + 49152);                         // 1
    float* v4 = mx + 1;                                       // 2,048 f

    taps_kernel<<<1, 512, 0, stream>>>(sigma, MA, MB, mx);

    // blur: K1 (z-axis, LDS-free) then fused K2 (y+x, scaled taps, max) -> X1 bf16 direct
    blur_k1<<<NB * NE * 50, 64, 0, stream>>>(x, W1, MA);
    blur_k2<<<NB * NE * 50, 64, 0, stream>>>(W1, MA, MB, X1, mx);

    // weight fragment packing
    wprep1_kernel<<<18, 64, 0, stream>>>(w1, wp1);
    wprep_kernel<<<27, 256, 0, stream>>>(w2, wp2, 32, 1, 4);
    wprep_kernel<<<108, 256, 0, stream>>>(w3, wp3, 64, 2, 8);

    // conv1: 4-xsel K-packing, XCD-swizzled
    conv1_mfma<<<3456, 64, 0, stream>>>(X1, wp1, b1, mx, X2);
    // conv2 / conv3 (XCD-swizzled inside)
    convN_mfma<24, 11, 32, 1, 4, 11, 2, 2, 11><<<3872, 64, 0, stream>>>(X2, wp2, b2, X3, 64);
    convN_mfma<11, 4, 64, 2, 8, 4, 1, 1, 4><<<1024, 64, 0, stream>>>(X3, wp3, b3, X4, 128);

    // conv4 (VALU, channels-last bf16 in) + head
    conv4_kernel<<<512, 256, 0, stream>>>(X4, w4, b4, v4);
    head_kernel<<<8, 128, 0, stream>>>(v4, fw1, fb1, fw2, fb2, out);
}